// Round 1
// baseline (670.024 us; speedup 1.0000x reference)
//
#include <hip/hip_runtime.h>
#include <math.h>

#pragma clang fp contract(off)

#define NB 4
#define NN 8000
#define NC 91
#define CM1 90
#define CAP 2048

// ws layout in 32-bit words
#define HIST_OFF 0            // NB*1024 ints
#define MAX_OFF 4096          // NB ints (float bits, atomicMax)
#define CNT_OFF 4100          // NB ints
#define TK_OFF 4104           // NB ints
#define BOX_OFF 4108          // NB*CAP*4 floats (float4 aligned: 4108*4 % 16 == 0)
#define SC_OFF (BOX_OFF + NB*CAP*4)
#define OID_OFF (SC_OFF + NB*CAP)

__constant__ float F_IMG_W = 1333.0f;
__constant__ float F_IMG_H = 800.0f;

__global__ void init_kernel(int* ws_i) {
  int i = blockIdx.x * blockDim.x + threadIdx.x;
  if (i < TK_OFF + NB) ws_i[i] = 0;
}

// PHASE 0: histogram valid scores + global box-coord max.
// PHASE 1: compact candidates with bin >= tkeep into per-image lists.
template <int PHASE>
__global__ void row_kernel(const float* __restrict__ logits,
                           const float* __restrict__ rel,
                           const float* __restrict__ props,
                           int* __restrict__ ws_i, float* __restrict__ ws_f) {
  const int row = blockIdx.x;          // b*NN + n
  const int b = row / NN;
  const int t = threadIdx.x;
  __shared__ float red[128];

  // softmax over 91 logits (matches jax.nn.softmax: exp(x-max)/sum)
  float l = (t < NC) ? logits[(size_t)row * NC + t] : -INFINITY;
  red[t] = l;
  __syncthreads();
  for (int s = 64; s > 0; s >>= 1) {
    if (t < s) red[t] = fmaxf(red[t], red[t + s]);
    __syncthreads();
  }
  float m = red[0];
  __syncthreads();
  float e = (t < NC) ? expf(l - m) : 0.0f;
  red[t] = e;
  __syncthreads();
  for (int s = 64; s > 0; s >>= 1) {
    if (t < s) red[t] += red[t + s];
    __syncthreads();
  }
  float sum = red[0];
  __syncthreads();

  float x1 = 0.f, y1 = 0.f, x2 = 0.f, y2 = 0.f, score = 0.f;
  float localmax = 0.0f;
  bool valid = false;
  if (t >= 1 && t < NC) {
    const int c = t;
    const float4 r = reinterpret_cast<const float4*>(rel + (size_t)row * (NC * 4))[c];
    const float px1 = props[(size_t)row * 4 + 0];
    const float py1 = props[(size_t)row * 4 + 1];
    const float px2 = props[(size_t)row * 4 + 2];
    const float py2 = props[(size_t)row * 4 + 3];
    const float w = px2 - px1, h = py2 - py1;
    const float cx = px1 + 0.5f * w, cy = py1 + 0.5f * h;
    const float dx = r.x / 10.0f, dy = r.y / 10.0f;
    const float dw = fminf(r.z / 5.0f, 4.135166556742356f);
    const float dh = fminf(r.w / 5.0f, 4.135166556742356f);
    const float pcx = dx * w + cx, pcy = dy * h + cy;
    const float pw = expf(dw) * w, ph = expf(dh) * h;
    x1 = pcx - 0.5f * pw; y1 = pcy - 0.5f * ph;
    x2 = pcx + 0.5f * pw; y2 = pcy + 0.5f * ph;
    x1 = fminf(fmaxf(x1, 0.0f), F_IMG_W);
    y1 = fminf(fmaxf(y1, 0.0f), F_IMG_H);
    x2 = fminf(fmaxf(x2, 0.0f), F_IMG_W);
    y2 = fminf(fmaxf(y2, 0.0f), F_IMG_H);
    score = e / sum;
    const float bw = x2 - x1, bh = y2 - y1;
    valid = (score > 0.05f) && (bw >= 0.01f) && (bh >= 0.01f);
    localmax = fmaxf(fmaxf(x1, y1), fmaxf(x2, y2));
  }

  if (PHASE == 0) {
    // global max over ALL candidate coords (valid or not) -> for per-class offset
    red[t] = localmax;
    __syncthreads();
    for (int s = 64; s > 0; s >>= 1) {
      if (t < s) red[t] = fmaxf(red[t], red[t + s]);
      __syncthreads();
    }
    if (t == 0) atomicMax(&ws_i[MAX_OFF + b], __float_as_int(red[0]));
    if (valid) {
      int bi = (int)(__float_as_uint(score) >> 16) - 15360;
      bi = min(max(bi, 0), 1023);
      atomicAdd(&ws_i[HIST_OFF + b * 1024 + bi], 1);
    }
  } else {
    const int tk = ws_i[TK_OFF + b];
    if (valid) {
      int bi = (int)(__float_as_uint(score) >> 16) - 15360;
      bi = min(max(bi, 0), 1023);
      if (bi >= tk) {
        const int pos = atomicAdd(&ws_i[CNT_OFF + b], 1);
        if (pos < CAP) {
          reinterpret_cast<float4*>(ws_f + BOX_OFF)[b * CAP + pos] =
              make_float4(x1, y1, x2, y2);
          ws_f[SC_OFF + b * CAP + pos] = score;
          const int n = row - b * NN;
          ws_i[OID_OFF + b * CAP + pos] = n * CM1 + (t - 1);
        }
      }
    }
  }
}

// Per image: find smallest bin t such that count(bins >= t) <= CAP.
__global__ void cutoff_kernel(int* __restrict__ ws_i) {
  const int b = blockIdx.x;
  const int t = threadIdx.x;
  __shared__ int seg[256];
  __shared__ int best;
  const int h0 = ws_i[HIST_OFF + b * 1024 + 4 * t + 0];
  const int h1 = ws_i[HIST_OFF + b * 1024 + 4 * t + 1];
  const int h2 = ws_i[HIST_OFF + b * 1024 + 4 * t + 2];
  const int h3 = ws_i[HIST_OFF + b * 1024 + 4 * t + 3];
  seg[t] = h0 + h1 + h2 + h3;
  if (t == 0) best = 1024;
  __syncthreads();
  for (int off = 1; off < 256; off <<= 1) {
    const int v = (t + off < 256) ? seg[t + off] : 0;
    __syncthreads();
    seg[t] += v;
    __syncthreads();
  }
  const int higher = (t < 255) ? seg[t + 1] : 0;  // count of bins >= 4*(t+1)
  int A = higher;
  int cand = 0x7FFFFFFF;
  A += h3; if (A <= CAP) cand = 4 * t + 3;
  A += h2; if (A <= CAP) cand = 4 * t + 2;
  A += h1; if (A <= CAP) cand = 4 * t + 1;
  A += h0; if (A <= CAP) cand = 4 * t + 0;
  if (cand != 0x7FFFFFFF) atomicMin(&best, cand);
  __syncthreads();
  if (t == 0) ws_i[TK_OFF + b] = best;
}

// One block per image: sequential 100-step argmax NMS fully in LDS.
__global__ void __launch_bounds__(256) nms_kernel(const int* __restrict__ ws_i,
                                                  const float* __restrict__ ws_f,
                                                  float* __restrict__ out) {
  const int b = blockIdx.x;
  const int t = threadIdx.x;
  __shared__ float bx[CAP][4];
  __shared__ float ssc[CAP];
  __shared__ float soffv[CAP];
  __shared__ int soid[CAP];
  __shared__ int selslot[100];
  __shared__ float selscore[100];
  __shared__ unsigned long long wkey[4];
  __shared__ int wslot[4];
  __shared__ int ctl[2];  // [0] selected slot / -1, [1] nacc

  int M = ws_i[CNT_OFF + b];
  if (M > CAP) M = CAP;
  const float maxp1 = __int_as_float(ws_i[MAX_OFF + b]) + 1.0f;

  for (int j = t; j < CAP; j += 256) {
    if (j < M) {
      const float4 v = reinterpret_cast<const float4*>(ws_f + BOX_OFF)[b * CAP + j];
      bx[j][0] = v.x; bx[j][1] = v.y; bx[j][2] = v.z; bx[j][3] = v.w;
      ssc[j] = ws_f[SC_OFF + b * CAP + j];
      const int oid = ws_i[OID_OFF + b * CAP + j];
      soid[j] = oid;
      soffv[j] = (float)(oid % CM1 + 1) * maxp1;  // label * (max+1), same as ref
    } else {
      bx[j][0] = bx[j][1] = bx[j][2] = bx[j][3] = 0.0f;
      ssc[j] = -INFINITY;
      soid[j] = 0x7FFFFFFF;
      soffv[j] = -1.0f;
    }
  }
  if (t == 0) ctl[1] = 0;
  __syncthreads();

  for (int it = 0; it < 100; ++it) {
    // --- argmax with first-index (smallest original id) tie-break ---
    unsigned long long key = 0;
    int slot = 0;
    for (int k2 = 0; k2 < CAP / 256; ++k2) {
      const int j = t + k2 * 256;
      const float s = ssc[j];
      unsigned u = __float_as_uint(s);
      u = (u & 0x80000000u) ? ~u : (u | 0x80000000u);
      const unsigned long long kk =
          ((unsigned long long)u << 32) | (unsigned)(0xFFFFFFFFu - (unsigned)soid[j]);
      if (kk > key) { key = kk; slot = j; }
    }
    for (int mm = 1; mm < 64; mm <<= 1) {
      const unsigned long long ok2 = __shfl_xor(key, mm);
      const int os = __shfl_xor(slot, mm);
      if (ok2 > key) { key = ok2; slot = os; }
    }
    if ((t & 63) == 0) { wkey[t >> 6] = key; wslot[t >> 6] = slot; }
    __syncthreads();
    if (t == 0) {
      unsigned long long bk = wkey[0];
      int bs = wslot[0];
      for (int i2 = 1; i2 < 4; ++i2)
        if (wkey[i2] > bk) { bk = wkey[i2]; bs = wslot[i2]; }
      const float bscore = ssc[bs];
      if (bscore > -5e29f) {  // si > NEG/2
        selslot[ctl[1]] = bs;
        selscore[ctl[1]] = bscore;
        ctl[1]++;
        ssc[bs] = -1e30f;
        ctl[0] = bs;
      } else {
        ctl[0] = -1;
      }
    }
    __syncthreads();
    const int sel = ctl[0];
    if (sel < 0) break;

    // --- suppress: offset-box IoU exactly as reference; cross-label IoU is 0 ---
    const float oi = soffv[sel];
    const float n0 = bx[sel][0] + oi, n1 = bx[sel][1] + oi;
    const float n2 = bx[sel][2] + oi, n3 = bx[sel][3] + oi;
    const float a1 = (n2 - n0) * (n3 - n1);
    for (int k2 = 0; k2 < CAP / 256; ++k2) {
      const int j = t + k2 * 256;
      if (soffv[j] == oi) {
        const float q0 = bx[j][0] + oi, q1 = bx[j][1] + oi;
        const float q2 = bx[j][2] + oi, q3 = bx[j][3] + oi;
        const float ix1 = fmaxf(n0, q0), iy1 = fmaxf(n1, q1);
        const float ix2 = fminf(n2, q2), iy2 = fminf(n3, q3);
        const float inter = fmaxf(ix2 - ix1, 0.0f) * fmaxf(iy2 - iy1, 0.0f);
        const float a2 = (q2 - q0) * (q3 - q1);
        const float iou = inter / ((a1 + a2) - inter);
        if (iou > 0.5f) ssc[j] = -1e30f;
      }
    }
    __syncthreads();
  }
  __syncthreads();
  const int nacc = ctl[1];

  // outputs: boxes [B,100,4] | scores [B,100] | labels [B,100] (as float)
  for (int k2 = t; k2 < 100; k2 += 256) {
    float o0 = 0.f, o1 = 0.f, o2 = 0.f, o3 = 0.f, sc = 0.f, lb = 0.f;
    if (k2 < nacc) {
      const int slot = selslot[k2];
      o0 = bx[slot][0]; o1 = bx[slot][1]; o2 = bx[slot][2]; o3 = bx[slot][3];
      sc = selscore[k2];
      lb = (float)(soid[slot] % CM1 + 1);
    }
    float* ob = out + ((size_t)b * 100 + k2) * 4;
    ob[0] = o0; ob[1] = o1; ob[2] = o2; ob[3] = o3;
    out[NB * 100 * 4 + b * 100 + k2] = sc;
    out[NB * 100 * 4 + NB * 100 + b * 100 + k2] = lb;
  }
}

extern "C" void kernel_launch(void* const* d_in, const int* in_sizes, int n_in,
                              void* d_out, int out_size, void* d_ws, size_t ws_size,
                              hipStream_t stream) {
  const float* logits = (const float*)d_in[0];
  const float* rel = (const float*)d_in[1];
  const float* props = (const float*)d_in[2];
  float* out = (float*)d_out;
  int* ws_i = (int*)d_ws;
  float* ws_f = (float*)d_ws;

  init_kernel<<<(TK_OFF + NB + 255) / 256, 256, 0, stream>>>(ws_i);
  row_kernel<0><<<NB * NN, 128, 0, stream>>>(logits, rel, props, ws_i, ws_f);
  cutoff_kernel<<<NB, 256, 0, stream>>>(ws_i);
  row_kernel<1><<<NB * NN, 128, 0, stream>>>(logits, rel, props, ws_i, ws_f);
  nms_kernel<<<NB, 256, 0, stream>>>(ws_i, ws_f, out);
}

// Round 2
// 643.231 us; speedup vs baseline: 1.0417x; 1.0417x over previous
//
#include <hip/hip_runtime.h>
#include <math.h>

#pragma clang fp contract(off)

#define NB 4
#define NN 8000
#define NC 91
#define CM1 90
#define CAP 2048
#define NCAND (NB * NN * CM1)   // 2,880,000 (divisible by 256)

// ws layout in 32-bit words
#define HIST_OFF 0            // NB*1024 ints
#define MAX_OFF 4096          // NB ints (float bits, atomicMax)
#define CNT_OFF 4100          // NB ints
#define TK_OFF 4104           // NB ints
#define BOX_OFF 4108          // NB*CAP*4 floats (float4 aligned)
#define SC_OFF (BOX_OFF + NB * CAP * 4)
#define OID_OFF (SC_OFF + NB * CAP)
#define RMAX_OFF (OID_OFF + NB * CAP)   // NB*NN floats
#define RSUM_OFF (RMAX_OFF + NB * NN)   // NB*NN floats

__constant__ float F_IMG_W = 1333.0f;
__constant__ float F_IMG_H = 800.0f;

__global__ void init_kernel(int* ws_i) {
  int i = blockIdx.x * blockDim.x + threadIdx.x;
  if (i < TK_OFF + NB) ws_i[i] = 0;
}

// One wave per row: softmax max + sum (exactly exp(x-max), summed).
__global__ void softmax_kernel(const float* __restrict__ logits,
                               float* __restrict__ ws_f) {
  const int wid = (blockIdx.x * blockDim.x + threadIdx.x) >> 6;
  const int lane = threadIdx.x & 63;
  if (wid >= NB * NN) return;
  const float* lp = logits + (size_t)wid * NC;
  const float l0 = lp[lane];                                  // 91 > 64: always valid
  const float l1 = (lane + 64 < NC) ? lp[lane + 64] : -INFINITY;
  float m = fmaxf(l0, l1);
  for (int mm = 32; mm; mm >>= 1) m = fmaxf(m, __shfl_xor(m, mm));
  float e = expf(l0 - m) + ((lane + 64 < NC) ? expf(l1 - m) : 0.0f);
  for (int mm = 32; mm; mm >>= 1) e += __shfl_xor(e, mm);
  if (lane == 0) {
    ws_f[RMAX_OFF + wid] = m;
    ws_f[RSUM_OFF + wid] = e;
  }
}

// Thread per (row, class>=1) candidate.
// PHASE 0: histogram of valid scores + global clipped-coord max.
// PHASE 1: compact candidates with bin >= tkeep into per-image lists.
template <int PHASE>
__global__ void cand_kernel(const float* __restrict__ logits,
                            const float* __restrict__ rel,
                            const float* __restrict__ props,
                            int* __restrict__ ws_i, float* __restrict__ ws_f) {
  const int cand = blockIdx.x * 256 + threadIdx.x;   // NCAND exactly divisible
  const int row = cand / CM1;
  const int c = cand - row * CM1 + 1;                // 1..90
  const int b = row / NN;
  const int lane = threadIdx.x & 63;

  // decode (identical op sequence to reference, no FMA contraction)
  const float4 r = reinterpret_cast<const float4*>(rel)[row * NC + c];
  const float4 p = reinterpret_cast<const float4*>(props)[row];
  const float w = p.z - p.x, h = p.w - p.y;
  const float cx = p.x + 0.5f * w, cy = p.y + 0.5f * h;
  const float dx = r.x / 10.0f, dy = r.y / 10.0f;
  const float dw = fminf(r.z / 5.0f, 4.135166556742356f);
  const float dh = fminf(r.w / 5.0f, 4.135166556742356f);
  const float pcx = dx * w + cx, pcy = dy * h + cy;
  const float pw = expf(dw) * w, ph = expf(dh) * h;
  float x1 = pcx - 0.5f * pw, y1 = pcy - 0.5f * ph;
  float x2 = pcx + 0.5f * pw, y2 = pcy + 0.5f * ph;
  x1 = fminf(fmaxf(x1, 0.0f), F_IMG_W);
  y1 = fminf(fmaxf(y1, 0.0f), F_IMG_H);
  x2 = fminf(fmaxf(x2, 0.0f), F_IMG_W);
  y2 = fminf(fmaxf(y2, 0.0f), F_IMG_H);

  const float l = logits[(size_t)row * NC + c];
  const float m = ws_f[RMAX_OFF + row];
  const float sum = ws_f[RSUM_OFF + row];
  const float score = expf(l - m) / sum;

  const float bw = x2 - x1, bh = y2 - y1;
  const bool valid = (score > 0.05f) && (bw >= 0.01f) && (bh >= 0.01f);
  int bi = (int)(__float_as_uint(score) >> 16) - 15360;
  bi = min(max(bi, 0), 1023);

  if (PHASE == 0) {
    // --- global coord max (over ALL candidates, classes 1..90) ---
    const float localmax = fmaxf(fmaxf(x1, y1), fmaxf(x2, y2));
    __shared__ int smax[NB];
    if (threadIdx.x < NB) smax[threadIdx.x] = 0;
    __syncthreads();
    int bits = __float_as_int(localmax);   // coords >= 0 so int-order == float-order
    const int bfirst = __shfl(b, 0);
    const bool hi = (b != bfirst);
    int v_lo = hi ? 0 : bits;
    int v_hi = hi ? bits : 0;
    int b_hi = hi ? b : 0;
    for (int mm = 32; mm; mm >>= 1) {
      v_lo = max(v_lo, __shfl_xor(v_lo, mm));
      v_hi = max(v_hi, __shfl_xor(v_hi, mm));
      b_hi = max(b_hi, __shfl_xor(b_hi, mm));
    }
    if (lane == 0) {
      atomicMax(&smax[bfirst], v_lo);
      if (v_hi > 0) atomicMax(&smax[b_hi], v_hi);
    }
    __syncthreads();
    if (threadIdx.x < NB && smax[threadIdx.x] > 0)
      atomicMax(&ws_i[MAX_OFF + threadIdx.x], smax[threadIdx.x]);
    if (valid) atomicAdd(&ws_i[HIST_OFF + b * 1024 + bi], 1);
  } else {
    const int tk = ws_i[TK_OFF + b];
    const bool keep = valid && (bi >= tk);
    // wave-aggregated compaction (order-free: NMS tie-breaks on oid)
    const unsigned long long keepm = __ballot(keep);
    const int bfirst = __shfl(b, 0);
    const unsigned long long firstm = __ballot(b == bfirst);
    if (keep) {
      const unsigned long long g =
          (b == bfirst) ? (keepm & firstm) : (keepm & ~firstm);
      const int leader = __ffsll(g) - 1;
      const int rank = __popcll(g & ((1ull << lane) - 1));
      int base = 0;
      if (lane == leader) base = atomicAdd(&ws_i[CNT_OFF + b], __popcll(g));
      base = __shfl(base, leader);
      const int pos = base + rank;
      if (pos < CAP) {
        reinterpret_cast<float4*>(ws_f + BOX_OFF)[b * CAP + pos] =
            make_float4(x1, y1, x2, y2);
        ws_f[SC_OFF + b * CAP + pos] = score;
        const int n = row - b * NN;
        ws_i[OID_OFF + b * CAP + pos] = n * CM1 + (c - 1);
      }
    }
  }
}

// Per image: find smallest bin t such that count(bins >= t) <= CAP.
__global__ void cutoff_kernel(int* __restrict__ ws_i) {
  const int b = blockIdx.x;
  const int t = threadIdx.x;
  __shared__ int seg[256];
  __shared__ int best;
  const int h0 = ws_i[HIST_OFF + b * 1024 + 4 * t + 0];
  const int h1 = ws_i[HIST_OFF + b * 1024 + 4 * t + 1];
  const int h2 = ws_i[HIST_OFF + b * 1024 + 4 * t + 2];
  const int h3 = ws_i[HIST_OFF + b * 1024 + 4 * t + 3];
  seg[t] = h0 + h1 + h2 + h3;
  if (t == 0) best = 1024;
  __syncthreads();
  for (int off = 1; off < 256; off <<= 1) {
    const int v = (t + off < 256) ? seg[t + off] : 0;
    __syncthreads();
    seg[t] += v;
    __syncthreads();
  }
  const int higher = (t < 255) ? seg[t + 1] : 0;
  int A = higher;
  int cand = 0x7FFFFFFF;
  A += h3; if (A <= CAP) cand = 4 * t + 3;
  A += h2; if (A <= CAP) cand = 4 * t + 2;
  A += h1; if (A <= CAP) cand = 4 * t + 1;
  A += h0; if (A <= CAP) cand = 4 * t + 0;
  if (cand != 0x7FFFFFFF) atomicMin(&best, cand);
  __syncthreads();
  if (t == 0) ws_i[TK_OFF + b] = best;
}

// One block per image: sequential 100-step argmax NMS fully in LDS.
__global__ void __launch_bounds__(256) nms_kernel(const int* __restrict__ ws_i,
                                                  const float* __restrict__ ws_f,
                                                  float* __restrict__ out) {
  const int b = blockIdx.x;
  const int t = threadIdx.x;
  __shared__ float bx[CAP][4];
  __shared__ float ssc[CAP];
  __shared__ float soffv[CAP];
  __shared__ int soid[CAP];
  __shared__ int selslot[100];
  __shared__ float selscore[100];
  __shared__ unsigned long long wkey[4];
  __shared__ int wslot[4];
  __shared__ int ctl[2];

  int M = ws_i[CNT_OFF + b];
  if (M > CAP) M = CAP;
  const float maxp1 = __int_as_float(ws_i[MAX_OFF + b]) + 1.0f;

  for (int j = t; j < CAP; j += 256) {
    if (j < M) {
      const float4 v = reinterpret_cast<const float4*>(ws_f + BOX_OFF)[b * CAP + j];
      bx[j][0] = v.x; bx[j][1] = v.y; bx[j][2] = v.z; bx[j][3] = v.w;
      ssc[j] = ws_f[SC_OFF + b * CAP + j];
      const int oid = ws_i[OID_OFF + b * CAP + j];
      soid[j] = oid;
      soffv[j] = (float)(oid % CM1 + 1) * maxp1;
    } else {
      bx[j][0] = bx[j][1] = bx[j][2] = bx[j][3] = 0.0f;
      ssc[j] = -INFINITY;
      soid[j] = 0x7FFFFFFF;
      soffv[j] = -1.0f;
    }
  }
  if (t == 0) ctl[1] = 0;
  __syncthreads();

  for (int it = 0; it < 100; ++it) {
    unsigned long long key = 0;
    int slot = 0;
    for (int k2 = 0; k2 < CAP / 256; ++k2) {
      const int j = t + k2 * 256;
      const float s = ssc[j];
      unsigned u = __float_as_uint(s);
      u = (u & 0x80000000u) ? ~u : (u | 0x80000000u);
      const unsigned long long kk =
          ((unsigned long long)u << 32) | (unsigned)(0xFFFFFFFFu - (unsigned)soid[j]);
      if (kk > key) { key = kk; slot = j; }
    }
    for (int mm = 1; mm < 64; mm <<= 1) {
      const unsigned long long ok2 = __shfl_xor(key, mm);
      const int os = __shfl_xor(slot, mm);
      if (ok2 > key) { key = ok2; slot = os; }
    }
    if ((t & 63) == 0) { wkey[t >> 6] = key; wslot[t >> 6] = slot; }
    __syncthreads();
    if (t == 0) {
      unsigned long long bk = wkey[0];
      int bs = wslot[0];
      for (int i2 = 1; i2 < 4; ++i2)
        if (wkey[i2] > bk) { bk = wkey[i2]; bs = wslot[i2]; }
      const float bscore = ssc[bs];
      if (bscore > -5e29f) {
        selslot[ctl[1]] = bs;
        selscore[ctl[1]] = bscore;
        ctl[1]++;
        ssc[bs] = -1e30f;
        ctl[0] = bs;
      } else {
        ctl[0] = -1;
      }
    }
    __syncthreads();
    const int sel = ctl[0];
    if (sel < 0) break;

    const float oi = soffv[sel];
    const float n0 = bx[sel][0] + oi, n1 = bx[sel][1] + oi;
    const float n2 = bx[sel][2] + oi, n3 = bx[sel][3] + oi;
    const float a1 = (n2 - n0) * (n3 - n1);
    for (int k2 = 0; k2 < CAP / 256; ++k2) {
      const int j = t + k2 * 256;
      if (soffv[j] == oi) {
        const float q0 = bx[j][0] + oi, q1 = bx[j][1] + oi;
        const float q2 = bx[j][2] + oi, q3 = bx[j][3] + oi;
        const float ix1 = fmaxf(n0, q0), iy1 = fmaxf(n1, q1);
        const float ix2 = fminf(n2, q2), iy2 = fminf(n3, q3);
        const float inter = fmaxf(ix2 - ix1, 0.0f) * fmaxf(iy2 - iy1, 0.0f);
        const float a2 = (q2 - q0) * (q3 - q1);
        const float iou = inter / ((a1 + a2) - inter);
        if (iou > 0.5f) ssc[j] = -1e30f;
      }
    }
    __syncthreads();
  }
  __syncthreads();
  const int nacc = ctl[1];

  for (int k2 = t; k2 < 100; k2 += 256) {
    float o0 = 0.f, o1 = 0.f, o2 = 0.f, o3 = 0.f, sc = 0.f, lb = 0.f;
    if (k2 < nacc) {
      const int slot = selslot[k2];
      o0 = bx[slot][0]; o1 = bx[slot][1]; o2 = bx[slot][2]; o3 = bx[slot][3];
      sc = selscore[k2];
      lb = (float)(soid[slot] % CM1 + 1);
    }
    float* ob = out + ((size_t)b * 100 + k2) * 4;
    ob[0] = o0; ob[1] = o1; ob[2] = o2; ob[3] = o3;
    out[NB * 100 * 4 + b * 100 + k2] = sc;
    out[NB * 100 * 4 + NB * 100 + b * 100 + k2] = lb;
  }
}

extern "C" void kernel_launch(void* const* d_in, const int* in_sizes, int n_in,
                              void* d_out, int out_size, void* d_ws, size_t ws_size,
                              hipStream_t stream) {
  const float* logits = (const float*)d_in[0];
  const float* rel = (const float*)d_in[1];
  const float* props = (const float*)d_in[2];
  float* out = (float*)d_out;
  int* ws_i = (int*)d_ws;
  float* ws_f = (float*)d_ws;

  init_kernel<<<(TK_OFF + NB + 255) / 256, 256, 0, stream>>>(ws_i);
  softmax_kernel<<<(NB * NN * 64) / 256, 256, 0, stream>>>(logits, ws_f);
  cand_kernel<0><<<NCAND / 256, 256, 0, stream>>>(logits, rel, props, ws_i, ws_f);
  cutoff_kernel<<<NB, 256, 0, stream>>>(ws_i);
  cand_kernel<1><<<NCAND / 256, 256, 0, stream>>>(logits, rel, props, ws_i, ws_f);
  nms_kernel<<<NB, 256, 0, stream>>>(ws_i, ws_f, out);
}

// Round 3
// 361.685 us; speedup vs baseline: 1.8525x; 1.7784x over previous
//
#include <hip/hip_runtime.h>
#include <math.h>

#pragma clang fp contract(off)

#define NB 4
#define NN 8000
#define NC 91
#define CM1 90
#define CAP 2048
#define GCAP 65536
#define RPB 16            // rows per block in cand_kernel
#define BPI (NN / RPB)    // 500 blocks per image
#define LCAP 320          // >= RPB*19 (hard bound: <=19 scores>0.05 per row)

// ws layout (32-bit words)
#define CNT_OFF 0   // NB
#define MAX_OFF 4   // NB
#define GBOX_OFF 16                        // NB*GCAP float4 (64B aligned)
#define GSC_OFF (GBOX_OFF + NB * GCAP * 4)
#define GOID_OFF (GSC_OFF + NB * GCAP)

__global__ void init_kernel(int* ws_i) {
  const int i = threadIdx.x;
  if (i < 8) ws_i[i] = 0;
}

// Fused: per-row softmax (wave shuffles) + decode + validity + per-image
// compaction. No per-thread global ws reads; 2 global atomics per block.
__global__ void __launch_bounds__(256) cand_kernel(const float* __restrict__ logits,
                                                   const float* __restrict__ rel,
                                                   const float* __restrict__ props,
                                                   int* __restrict__ ws_i,
                                                   float* __restrict__ ws_f) {
  const int blk = blockIdx.x;
  const int b = blk / BPI;
  const int t = threadIdx.x;
  const int lane = t & 63;
  const int wid = t >> 6;

  __shared__ float sbx[LCAP][4];
  __shared__ float ssb[LCAP];
  __shared__ int soidb[LCAP];
  __shared__ int scnt;
  __shared__ int smaxs;
  __shared__ int sgbase;
  if (t == 0) { scnt = 0; smaxs = 0; }
  __syncthreads();

  int tmax = 0;  // thread-local coord max (float bits; coords >= 0)

  for (int i = 0; i < 4; ++i) {
    const int row = blk * RPB + wid * 4 + i;
    const float* lp = logits + (size_t)row * NC;
    // softmax stats via wave shuffles (exp(x-max), summed) — matches jax
    const float l0 = lp[lane];
    const bool hi = (lane + 64 < NC);
    const float l1 = hi ? lp[lane + 64] : -INFINITY;
    float m = fmaxf(l0, l1);
    for (int mm = 32; mm; mm >>= 1) m = fmaxf(m, __shfl_xor(m, mm));
    float sum = expf(l0 - m) + (hi ? expf(l1 - m) : 0.0f);
    for (int mm = 32; mm; mm >>= 1) sum += __shfl_xor(sum, mm);

    const float4 p = reinterpret_cast<const float4*>(props)[row];
    const float w = p.z - p.x, h = p.w - p.y;
    const float cx = p.x + 0.5f * w, cy = p.y + 0.5f * h;

    for (int pp = 0; pp < 2; ++pp) {
      const int c = 1 + lane + 64 * pp;
      bool valid = false;
      float x1 = 0.f, y1 = 0.f, x2 = 0.f, y2 = 0.f, score = 0.f;
      if (c < NC) {
        const float lc = lp[c];
        const float4 r = reinterpret_cast<const float4*>(rel)[(size_t)row * NC + c];
        const float dx = r.x / 10.0f, dy = r.y / 10.0f;
        const float dw = fminf(r.z / 5.0f, 4.135166556742356f);
        const float dh = fminf(r.w / 5.0f, 4.135166556742356f);
        const float pcx = dx * w + cx, pcy = dy * h + cy;
        const float pw = expf(dw) * w, ph = expf(dh) * h;
        x1 = pcx - 0.5f * pw; y1 = pcy - 0.5f * ph;
        x2 = pcx + 0.5f * pw; y2 = pcy + 0.5f * ph;
        x1 = fminf(fmaxf(x1, 0.0f), 1333.0f);
        y1 = fminf(fmaxf(y1, 0.0f), 800.0f);
        x2 = fminf(fmaxf(x2, 0.0f), 1333.0f);
        y2 = fminf(fmaxf(y2, 0.0f), 800.0f);
        score = expf(lc - m) / sum;
        const float localmax = fmaxf(fmaxf(x1, y1), fmaxf(x2, y2));
        tmax = max(tmax, __float_as_int(localmax));
        const float bw = x2 - x1, bh = y2 - y1;
        valid = (score > 0.05f) && (bw >= 0.01f) && (bh >= 0.01f);
      }
      const unsigned long long mk = __ballot(valid);
      if (valid) {
        const int leader = __ffsll(mk) - 1;
        const int rank = __popcll(mk & ((1ull << lane) - 1));
        int basel = 0;
        if (lane == leader) basel = atomicAdd(&scnt, __popcll(mk));
        basel = __shfl(basel, leader);
        const int slot = basel + rank;  // <= LCAP by the 19/row bound
        sbx[slot][0] = x1; sbx[slot][1] = y1; sbx[slot][2] = x2; sbx[slot][3] = y2;
        ssb[slot] = score;
        soidb[slot] = (row - b * NN) * CM1 + (c - 1);
      }
    }
  }
  atomicMax(&smaxs, tmax);  // LDS atomic
  __syncthreads();
  const int n = scnt;
  if (t == 0) {
    sgbase = atomicAdd(&ws_i[CNT_OFF + b], n);
    atomicMax(&ws_i[MAX_OFF + b], smaxs);
  }
  __syncthreads();
  const int gb = sgbase;
  for (int j = t; j < n; j += 256) {
    const int pos = gb + j;
    if (pos < GCAP) {
      reinterpret_cast<float4*>(ws_f + GBOX_OFF)[b * GCAP + pos] =
          make_float4(sbx[j][0], sbx[j][1], sbx[j][2], sbx[j][3]);
      ws_f[GSC_OFF + b * GCAP + pos] = ssb[j];
      ws_i[GOID_OFF + b * GCAP + pos] = soidb[j];
    }
  }
}

// One block per image: LDS histogram -> cutoff -> LDS compact -> 100-step NMS.
__global__ void __launch_bounds__(256) nms_kernel(const int* __restrict__ ws_i,
                                                  const float* __restrict__ ws_f,
                                                  float* __restrict__ out) {
  const int b = blockIdx.x;
  const int t = threadIdx.x;
  __shared__ int hist[1024];
  __shared__ int seg[256];
  __shared__ float bx[CAP][4];
  __shared__ float ssc[CAP];
  __shared__ float soffv[CAP];
  __shared__ int soid[CAP];
  __shared__ int selslot[100];
  __shared__ float selscore[100];
  __shared__ unsigned long long wkey[4];
  __shared__ int wslot[4];
  __shared__ int bestt;
  __shared__ int cnt2;
  __shared__ int ctl[2];

  int M = ws_i[CNT_OFF + b];
  if (M > GCAP) M = GCAP;
  const float maxp1 = __int_as_float(ws_i[MAX_OFF + b]) + 1.0f;
  const float* gsc = ws_f + GSC_OFF + (size_t)b * GCAP;
  const int* goid = ws_i + GOID_OFF + (size_t)b * GCAP;
  const float4* gbox = reinterpret_cast<const float4*>(ws_f + GBOX_OFF) + (size_t)b * GCAP;

  for (int j = t; j < 1024; j += 256) hist[j] = 0;
  if (t == 0) { bestt = 1024; cnt2 = 0; ctl[1] = 0; }
  __syncthreads();

  for (int j = t; j < M; j += 256) {
    const float s = gsc[j];
    int bi = (int)(__float_as_uint(s) >> 16) - 15360;
    bi = min(max(bi, 0), 1023);
    atomicAdd(&hist[bi], 1);
  }
  __syncthreads();

  // cutoff: smallest bin tk with count(bins >= tk) <= CAP
  const int h0 = hist[4 * t + 0], h1 = hist[4 * t + 1];
  const int h2 = hist[4 * t + 2], h3 = hist[4 * t + 3];
  seg[t] = h0 + h1 + h2 + h3;
  __syncthreads();
  for (int off = 1; off < 256; off <<= 1) {
    const int v = (t + off < 256) ? seg[t + off] : 0;
    __syncthreads();
    seg[t] += v;
    __syncthreads();
  }
  {
    const int higher = (t < 255) ? seg[t + 1] : 0;
    int A = higher;
    int cnd = 0x7FFFFFFF;
    A += h3; if (A <= CAP) cnd = 4 * t + 3;
    A += h2; if (A <= CAP) cnd = 4 * t + 2;
    A += h1; if (A <= CAP) cnd = 4 * t + 1;
    A += h0; if (A <= CAP) cnd = 4 * t + 0;
    if (cnd != 0x7FFFFFFF) atomicMin(&bestt, cnd);
  }
  __syncthreads();
  const int tk = bestt;

  // init all slots, then compact survivors into LDS
  for (int j = t; j < CAP; j += 256) {
    bx[j][0] = bx[j][1] = bx[j][2] = bx[j][3] = 0.0f;
    ssc[j] = -INFINITY;
    soid[j] = 0x7FFFFFFF;
    soffv[j] = -1.0f;
  }
  __syncthreads();
  for (int j = t; j < M; j += 256) {
    const float s = gsc[j];
    int bi = (int)(__float_as_uint(s) >> 16) - 15360;
    bi = min(max(bi, 0), 1023);
    if (bi >= tk) {
      const int pos = atomicAdd(&cnt2, 1);  // <= CAP by cutoff construction
      const float4 v = gbox[j];
      bx[pos][0] = v.x; bx[pos][1] = v.y; bx[pos][2] = v.z; bx[pos][3] = v.w;
      ssc[pos] = s;
      const int oid = goid[j];
      soid[pos] = oid;
      soffv[pos] = (float)(oid % CM1 + 1) * maxp1;
    }
  }
  __syncthreads();

  for (int it = 0; it < 100; ++it) {
    // argmax with first-index (smallest oid) tie-break
    unsigned long long key = 0;
    int slot = 0;
    for (int k2 = 0; k2 < CAP / 256; ++k2) {
      const int j = t + k2 * 256;
      const float s = ssc[j];
      unsigned u = __float_as_uint(s);
      u = (u & 0x80000000u) ? ~u : (u | 0x80000000u);
      const unsigned long long kk =
          ((unsigned long long)u << 32) | (unsigned)(0xFFFFFFFFu - (unsigned)soid[j]);
      if (kk > key) { key = kk; slot = j; }
    }
    for (int mm = 1; mm < 64; mm <<= 1) {
      const unsigned long long ok2 = __shfl_xor(key, mm);
      const int os = __shfl_xor(slot, mm);
      if (ok2 > key) { key = ok2; slot = os; }
    }
    if ((t & 63) == 0) { wkey[t >> 6] = key; wslot[t >> 6] = slot; }
    __syncthreads();
    if (t == 0) {
      unsigned long long bk = wkey[0];
      int bs = wslot[0];
      for (int i2 = 1; i2 < 4; ++i2)
        if (wkey[i2] > bk) { bk = wkey[i2]; bs = wslot[i2]; }
      const float bscore = ssc[bs];
      if (bscore > -5e29f) {
        selslot[ctl[1]] = bs;
        selscore[ctl[1]] = bscore;
        ctl[1]++;
        ssc[bs] = -1e30f;
        ctl[0] = bs;
      } else {
        ctl[0] = -1;
      }
    }
    __syncthreads();
    const int sel = ctl[0];
    if (sel < 0) break;

    // suppress same-label boxes with IoU > 0.5 (offset-box arithmetic == ref)
    const float oi = soffv[sel];
    const float n0 = bx[sel][0] + oi, n1 = bx[sel][1] + oi;
    const float n2 = bx[sel][2] + oi, n3 = bx[sel][3] + oi;
    const float a1 = (n2 - n0) * (n3 - n1);
    for (int k2 = 0; k2 < CAP / 256; ++k2) {
      const int j = t + k2 * 256;
      if (soffv[j] == oi) {
        const float q0 = bx[j][0] + oi, q1 = bx[j][1] + oi;
        const float q2 = bx[j][2] + oi, q3 = bx[j][3] + oi;
        const float ix1 = fmaxf(n0, q0), iy1 = fmaxf(n1, q1);
        const float ix2 = fminf(n2, q2), iy2 = fminf(n3, q3);
        const float inter = fmaxf(ix2 - ix1, 0.0f) * fmaxf(iy2 - iy1, 0.0f);
        const float a2 = (q2 - q0) * (q3 - q1);
        const float iou = inter / ((a1 + a2) - inter);
        if (iou > 0.5f) ssc[j] = -1e30f;
      }
    }
    __syncthreads();
  }
  __syncthreads();
  const int nacc = ctl[1];

  for (int k2 = t; k2 < 100; k2 += 256) {
    float o0 = 0.f, o1 = 0.f, o2 = 0.f, o3 = 0.f, sc = 0.f, lb = 0.f;
    if (k2 < nacc) {
      const int slot = selslot[k2];
      o0 = bx[slot][0]; o1 = bx[slot][1]; o2 = bx[slot][2]; o3 = bx[slot][3];
      sc = selscore[k2];
      lb = (float)(soid[slot] % CM1 + 1);
    }
    float* ob = out + ((size_t)b * 100 + k2) * 4;
    ob[0] = o0; ob[1] = o1; ob[2] = o2; ob[3] = o3;
    out[NB * 100 * 4 + b * 100 + k2] = sc;
    out[NB * 100 * 4 + NB * 100 + b * 100 + k2] = lb;
  }
}

extern "C" void kernel_launch(void* const* d_in, const int* in_sizes, int n_in,
                              void* d_out, int out_size, void* d_ws, size_t ws_size,
                              hipStream_t stream) {
  const float* logits = (const float*)d_in[0];
  const float* rel = (const float*)d_in[1];
  const float* props = (const float*)d_in[2];
  float* out = (float*)d_out;
  int* ws_i = (int*)d_ws;
  float* ws_f = (float*)d_ws;

  init_kernel<<<1, 256, 0, stream>>>(ws_i);
  cand_kernel<<<NB * BPI, 256, 0, stream>>>(logits, rel, props, ws_i, ws_f);
  nms_kernel<<<NB, 256, 0, stream>>>(ws_i, ws_f, out);
}

// Round 4
// 323.902 us; speedup vs baseline: 2.0686x; 1.1166x over previous
//
#include <hip/hip_runtime.h>
#include <math.h>

#pragma clang fp contract(off)

#define NB 4
#define NN 8000
#define NC 91
#define CM1 90
#define CAP 2048
#define GCAP 65536
#define RPB 16            // rows per block in cand_kernel
#define BPI (NN / RPB)    // 500 blocks per image
#define LCAP 320          // >= RPB*19 (hard bound: <=19 scores>0.05 per row)

// ws layout (32-bit words)
#define CNT_OFF 0   // NB
#define MAX_OFF 4   // NB
#define GBOX_OFF 16                        // NB*GCAP float4 (64B aligned)
#define GSC_OFF (GBOX_OFF + NB * GCAP * 4)
#define GOID_OFF (GSC_OFF + NB * GCAP)

__global__ void init_kernel(int* ws_i) {
  const int i = threadIdx.x;
  if (i < 8) ws_i[i] = 0;
}

// Fused: per-row softmax (wave shuffles) + decode + validity + per-image
// compaction. No per-thread global ws reads; 2 global atomics per block.
__global__ void __launch_bounds__(256) cand_kernel(const float* __restrict__ logits,
                                                   const float* __restrict__ rel,
                                                   const float* __restrict__ props,
                                                   int* __restrict__ ws_i,
                                                   float* __restrict__ ws_f) {
  const int blk = blockIdx.x;
  const int b = blk / BPI;
  const int t = threadIdx.x;
  const int lane = t & 63;
  const int wid = t >> 6;

  __shared__ float sbx[LCAP][4];
  __shared__ float ssb[LCAP];
  __shared__ int soidb[LCAP];
  __shared__ int scnt;
  __shared__ int smaxs;
  __shared__ int sgbase;
  if (t == 0) { scnt = 0; smaxs = 0; }
  __syncthreads();

  int tmax = 0;  // thread-local coord max (float bits; coords >= 0)

  for (int i = 0; i < 4; ++i) {
    const int row = blk * RPB + wid * 4 + i;
    const float* lp = logits + (size_t)row * NC;
    const float l0 = lp[lane];
    const bool hi = (lane + 64 < NC);
    const float l1 = hi ? lp[lane + 64] : -INFINITY;
    float m = fmaxf(l0, l1);
    for (int mm = 32; mm; mm >>= 1) m = fmaxf(m, __shfl_xor(m, mm));
    float sum = expf(l0 - m) + (hi ? expf(l1 - m) : 0.0f);
    for (int mm = 32; mm; mm >>= 1) sum += __shfl_xor(sum, mm);

    const float4 p = reinterpret_cast<const float4*>(props)[row];
    const float w = p.z - p.x, h = p.w - p.y;
    const float cx = p.x + 0.5f * w, cy = p.y + 0.5f * h;

    for (int pp = 0; pp < 2; ++pp) {
      const int c = 1 + lane + 64 * pp;
      bool valid = false;
      float x1 = 0.f, y1 = 0.f, x2 = 0.f, y2 = 0.f, score = 0.f;
      if (c < NC) {
        const float lc = lp[c];
        const float4 r = reinterpret_cast<const float4*>(rel)[(size_t)row * NC + c];
        const float dx = r.x / 10.0f, dy = r.y / 10.0f;
        const float dw = fminf(r.z / 5.0f, 4.135166556742356f);
        const float dh = fminf(r.w / 5.0f, 4.135166556742356f);
        const float pcx = dx * w + cx, pcy = dy * h + cy;
        const float pw = expf(dw) * w, ph = expf(dh) * h;
        x1 = pcx - 0.5f * pw; y1 = pcy - 0.5f * ph;
        x2 = pcx + 0.5f * pw; y2 = pcy + 0.5f * ph;
        x1 = fminf(fmaxf(x1, 0.0f), 1333.0f);
        y1 = fminf(fmaxf(y1, 0.0f), 800.0f);
        x2 = fminf(fmaxf(x2, 0.0f), 1333.0f);
        y2 = fminf(fmaxf(y2, 0.0f), 800.0f);
        score = expf(lc - m) / sum;
        const float localmax = fmaxf(fmaxf(x1, y1), fmaxf(x2, y2));
        tmax = max(tmax, __float_as_int(localmax));
        const float bw = x2 - x1, bh = y2 - y1;
        valid = (score > 0.05f) && (bw >= 0.01f) && (bh >= 0.01f);
      }
      const unsigned long long mk = __ballot(valid);
      if (valid) {
        const int leader = __ffsll(mk) - 1;
        const int rank = __popcll(mk & ((1ull << lane) - 1));
        int basel = 0;
        if (lane == leader) basel = atomicAdd(&scnt, __popcll(mk));
        basel = __shfl(basel, leader);
        const int slot = basel + rank;
        sbx[slot][0] = x1; sbx[slot][1] = y1; sbx[slot][2] = x2; sbx[slot][3] = y2;
        ssb[slot] = score;
        soidb[slot] = (row - b * NN) * CM1 + (c - 1);
      }
    }
  }
  atomicMax(&smaxs, tmax);  // LDS atomic
  __syncthreads();
  const int n = scnt;
  if (t == 0) {
    sgbase = atomicAdd(&ws_i[CNT_OFF + b], n);
    atomicMax(&ws_i[MAX_OFF + b], smaxs);
  }
  __syncthreads();
  const int gb = sgbase;
  for (int j = t; j < n; j += 256) {
    const int pos = gb + j;
    if (pos < GCAP) {
      reinterpret_cast<float4*>(ws_f + GBOX_OFF)[b * GCAP + pos] =
          make_float4(sbx[j][0], sbx[j][1], sbx[j][2], sbx[j][3]);
      ws_f[GSC_OFF + b * GCAP + pos] = ssb[j];
      ws_i[GOID_OFF + b * GCAP + pos] = soidb[j];
    }
  }
}

// One block per image: LDS histogram -> cutoff -> LDS compact -> register-
// resident 100-step argmax NMS (1 barrier / iteration).
__global__ void __launch_bounds__(256) nms_kernel(const int* __restrict__ ws_i,
                                                  const float* __restrict__ ws_f,
                                                  float* __restrict__ out) {
  const int b = blockIdx.x;
  const int t = threadIdx.x;
  __shared__ float4 bx4[CAP];
  __shared__ float ssc[CAP];
  __shared__ float soffv[CAP];
  __shared__ int soid[CAP];
  __shared__ int hist[1024];
  __shared__ int seg[256];
  __shared__ int selslot[100];
  __shared__ float selscore[100];
  __shared__ unsigned long long wkey[2][4];
  __shared__ int wslot[2][4];
  __shared__ int bestt;
  __shared__ int cnt2;

  int M = ws_i[CNT_OFF + b];
  if (M > GCAP) M = GCAP;
  const float maxp1 = __int_as_float(ws_i[MAX_OFF + b]) + 1.0f;
  const float* gsc = ws_f + GSC_OFF + (size_t)b * GCAP;
  const int* goid = ws_i + GOID_OFF + (size_t)b * GCAP;
  const float4* gbox = reinterpret_cast<const float4*>(ws_f + GBOX_OFF) + (size_t)b * GCAP;

  for (int j = t; j < 1024; j += 256) hist[j] = 0;
  if (t == 0) { bestt = 1024; cnt2 = 0; }
  __syncthreads();

  for (int j = t; j < M; j += 256) {
    const float s = gsc[j];
    int bi = (int)(__float_as_uint(s) >> 16) - 15360;
    bi = min(max(bi, 0), 1023);
    atomicAdd(&hist[bi], 1);
  }
  __syncthreads();

  // cutoff: smallest bin tk with count(bins >= tk) <= CAP
  const int h0 = hist[4 * t + 0], h1 = hist[4 * t + 1];
  const int h2 = hist[4 * t + 2], h3 = hist[4 * t + 3];
  seg[t] = h0 + h1 + h2 + h3;
  __syncthreads();
  for (int off = 1; off < 256; off <<= 1) {
    const int v = (t + off < 256) ? seg[t + off] : 0;
    __syncthreads();
    seg[t] += v;
    __syncthreads();
  }
  {
    const int higher = (t < 255) ? seg[t + 1] : 0;
    int A = higher;
    int cnd = 0x7FFFFFFF;
    A += h3; if (A <= CAP) cnd = 4 * t + 3;
    A += h2; if (A <= CAP) cnd = 4 * t + 2;
    A += h1; if (A <= CAP) cnd = 4 * t + 1;
    A += h0; if (A <= CAP) cnd = 4 * t + 0;
    if (cnd != 0x7FFFFFFF) atomicMin(&bestt, cnd);
  }
  __syncthreads();
  const int tk = bestt;

  for (int j = t; j < CAP; j += 256) {
    bx4[j] = make_float4(0.f, 0.f, 0.f, 0.f);
    ssc[j] = -INFINITY;
    soid[j] = 0x7FFFFFFF;
    soffv[j] = -1.0f;
  }
  __syncthreads();
  for (int j = t; j < M; j += 256) {
    const float s = gsc[j];
    int bi = (int)(__float_as_uint(s) >> 16) - 15360;
    bi = min(max(bi, 0), 1023);
    if (bi >= tk) {
      const int pos = atomicAdd(&cnt2, 1);  // <= CAP by cutoff construction
      bx4[pos] = gbox[j];
      ssc[pos] = s;
      const int oid = goid[j];
      soid[pos] = oid;
      soffv[pos] = (float)(oid % CM1 + 1) * maxp1;
    }
  }
  __syncthreads();

  // ---- load this thread's 8 slots into registers ----
  unsigned long long k[8];
  float x1r[8], y1r[8], x2r[8], y2r[8], ofr[8];
#pragma unroll
  for (int r = 0; r < 8; ++r) {
    const int j = t + 256 * r;
    const float s = ssc[j];
    unsigned long long kk = 0;
    if (s > 0.0f) {  // live slots have score > 0.05
      const unsigned u = __float_as_uint(s) | 0x80000000u;
      kk = ((unsigned long long)u << 32) |
           (unsigned)(0xFFFFFFFFu - (unsigned)soid[j]);
    }
    k[r] = kk;
    const float4 v = bx4[j];
    x1r[r] = v.x; y1r[r] = v.y; x2r[r] = v.z; y2r[r] = v.w;
    ofr[r] = soffv[j];
  }

  int nacc = 0;
  int p = 0;
  for (int it = 0; it < 100; ++it) {
    // local argmax over 8 register slots
    unsigned long long bk = k[0];
    int br = 0;
#pragma unroll
    for (int r = 1; r < 8; ++r)
      if (k[r] > bk) { bk = k[r]; br = r; }
    int bslot = t + 256 * br;
    // wave reduce (keys are unique: oid embedded)
    for (int mm = 1; mm < 64; mm <<= 1) {
      const unsigned long long ok = __shfl_xor(bk, mm);
      const int os = __shfl_xor(bslot, mm);
      if (ok > bk) { bk = ok; bslot = os; }
    }
    if ((t & 63) == 0) { wkey[p][t >> 6] = bk; wslot[p][t >> 6] = bslot; }
    __syncthreads();
    unsigned long long gk = wkey[p][0];
    int gs = wslot[p][0];
#pragma unroll
    for (int i2 = 1; i2 < 4; ++i2) {
      const unsigned long long ok = wkey[p][i2];
      if (ok > gk) { gk = ok; gs = wslot[p][i2]; }
    }
    if (gk == 0) break;  // uniform: all remaining dead
    if (t == 0) {
      selslot[it] = gs;
      selscore[it] = __uint_as_float((unsigned)(gk >> 32) & 0x7FFFFFFFu);
    }
    nacc = it + 1;
    // owner clears selected slot
#pragma unroll
    for (int r = 0; r < 8; ++r)
      if (gs == t + 256 * r) k[r] = 0;
    // broadcast selected box (constant LDS, same-address read)
    const float4 nb = bx4[gs];
    const float oi = soffv[gs];
    const float n0 = nb.x + oi, n1 = nb.y + oi;
    const float n2 = nb.z + oi, n3 = nb.w + oi;
    const float a1 = (n2 - n0) * (n3 - n1);
#pragma unroll
    for (int r = 0; r < 8; ++r) {
      if (ofr[r] == oi && k[r] != 0) {
        const float q0 = x1r[r] + oi, q1 = y1r[r] + oi;
        const float q2 = x2r[r] + oi, q3 = y2r[r] + oi;
        const float ix1 = fmaxf(n0, q0), iy1 = fmaxf(n1, q1);
        const float ix2 = fminf(n2, q2), iy2 = fminf(n3, q3);
        const float inter = fmaxf(ix2 - ix1, 0.0f) * fmaxf(iy2 - iy1, 0.0f);
        const float a2 = (q2 - q0) * (q3 - q1);
        const float iou = inter / ((a1 + a2) - inter);
        if (iou > 0.5f) k[r] = 0;
      }
    }
    p ^= 1;
  }
  __syncthreads();

  for (int k2 = t; k2 < 100; k2 += 256) {
    float o0 = 0.f, o1 = 0.f, o2 = 0.f, o3 = 0.f, sc = 0.f, lb = 0.f;
    if (k2 < nacc) {
      const int slot = selslot[k2];
      const float4 v = bx4[slot];
      o0 = v.x; o1 = v.y; o2 = v.z; o3 = v.w;
      sc = selscore[k2];
      lb = (float)(soid[slot] % CM1 + 1);
    }
    float* ob = out + ((size_t)b * 100 + k2) * 4;
    ob[0] = o0; ob[1] = o1; ob[2] = o2; ob[3] = o3;
    out[NB * 100 * 4 + b * 100 + k2] = sc;
    out[NB * 100 * 4 + NB * 100 + b * 100 + k2] = lb;
  }
}

extern "C" void kernel_launch(void* const* d_in, const int* in_sizes, int n_in,
                              void* d_out, int out_size, void* d_ws, size_t ws_size,
                              hipStream_t stream) {
  const float* logits = (const float*)d_in[0];
  const float* rel = (const float*)d_in[1];
  const float* props = (const float*)d_in[2];
  float* out = (float*)d_out;
  int* ws_i = (int*)d_ws;
  float* ws_f = (float*)d_ws;

  init_kernel<<<1, 256, 0, stream>>>(ws_i);
  cand_kernel<<<NB * BPI, 256, 0, stream>>>(logits, rel, props, ws_i, ws_f);
  nms_kernel<<<NB, 256, 0, stream>>>(ws_i, ws_f, out);
}

// Round 5
// 286.128 us; speedup vs baseline: 2.3417x; 1.1320x over previous
//
#include <hip/hip_runtime.h>
#include <math.h>

#pragma clang fp contract(off)

#define NB 4
#define NN 8000
#define NC 91
#define CM1 90
#define CAP 2048
#define GCAP 65536
#define RPB 16            // rows per block in cand_kernel
#define BPI (NN / RPB)    // 500 blocks per image
#define LCAP 320          // >= RPB*19 (hard bound: <=19 scores>0.05 per row)

// ws layout (32-bit words)
#define CNT_OFF 0   // NB
#define MAX_OFF 4   // NB
#define GBOX_OFF 16                        // NB*GCAP float4 (64B aligned)
#define GSC_OFF (GBOX_OFF + NB * GCAP * 4)
#define GOID_OFF (GSC_OFF + NB * GCAP)

__global__ void init_kernel(int* ws_i) {
  const int i = threadIdx.x;
  if (i < 8) ws_i[i] = 0;
}

// Fused: per-row softmax (wave shuffles) + decode + validity + per-image
// compaction. No per-thread global ws reads; 2 global atomics per block.
__global__ void __launch_bounds__(256) cand_kernel(const float* __restrict__ logits,
                                                   const float* __restrict__ rel,
                                                   const float* __restrict__ props,
                                                   int* __restrict__ ws_i,
                                                   float* __restrict__ ws_f) {
  const int blk = blockIdx.x;
  const int b = blk / BPI;
  const int t = threadIdx.x;
  const int lane = t & 63;
  const int wid = t >> 6;

  __shared__ float sbx[LCAP][4];
  __shared__ float ssb[LCAP];
  __shared__ int soidb[LCAP];
  __shared__ int scnt;
  __shared__ int smaxs;
  __shared__ int sgbase;
  if (t == 0) { scnt = 0; smaxs = 0; }
  __syncthreads();

  int tmax = 0;  // thread-local coord max (float bits; coords >= 0)

  for (int i = 0; i < 4; ++i) {
    const int row = blk * RPB + wid * 4 + i;
    const float* lp = logits + (size_t)row * NC;
    const float l0 = lp[lane];
    const bool hi = (lane + 64 < NC);
    const float l1 = hi ? lp[lane + 64] : -INFINITY;
    float m = fmaxf(l0, l1);
    for (int mm = 32; mm; mm >>= 1) m = fmaxf(m, __shfl_xor(m, mm));
    float sum = expf(l0 - m) + (hi ? expf(l1 - m) : 0.0f);
    for (int mm = 32; mm; mm >>= 1) sum += __shfl_xor(sum, mm);

    const float4 p = reinterpret_cast<const float4*>(props)[row];
    const float w = p.z - p.x, h = p.w - p.y;
    const float cx = p.x + 0.5f * w, cy = p.y + 0.5f * h;

    for (int pp = 0; pp < 2; ++pp) {
      const int c = 1 + lane + 64 * pp;
      bool valid = false;
      float x1 = 0.f, y1 = 0.f, x2 = 0.f, y2 = 0.f, score = 0.f;
      if (c < NC) {
        const float lc = lp[c];
        const float4 r = reinterpret_cast<const float4*>(rel)[(size_t)row * NC + c];
        const float dx = r.x / 10.0f, dy = r.y / 10.0f;
        const float dw = fminf(r.z / 5.0f, 4.135166556742356f);
        const float dh = fminf(r.w / 5.0f, 4.135166556742356f);
        const float pcx = dx * w + cx, pcy = dy * h + cy;
        const float pw = expf(dw) * w, ph = expf(dh) * h;
        x1 = pcx - 0.5f * pw; y1 = pcy - 0.5f * ph;
        x2 = pcx + 0.5f * pw; y2 = pcy + 0.5f * ph;
        x1 = fminf(fmaxf(x1, 0.0f), 1333.0f);
        y1 = fminf(fmaxf(y1, 0.0f), 800.0f);
        x2 = fminf(fmaxf(x2, 0.0f), 1333.0f);
        y2 = fminf(fmaxf(y2, 0.0f), 800.0f);
        score = expf(lc - m) / sum;
        const float localmax = fmaxf(fmaxf(x1, y1), fmaxf(x2, y2));
        tmax = max(tmax, __float_as_int(localmax));
        const float bw = x2 - x1, bh = y2 - y1;
        valid = (score > 0.05f) && (bw >= 0.01f) && (bh >= 0.01f);
      }
      const unsigned long long mk = __ballot(valid);
      if (valid) {
        const int leader = __ffsll(mk) - 1;
        const int rank = __popcll(mk & ((1ull << lane) - 1));
        int basel = 0;
        if (lane == leader) basel = atomicAdd(&scnt, __popcll(mk));
        basel = __shfl(basel, leader);
        const int slot = basel + rank;
        sbx[slot][0] = x1; sbx[slot][1] = y1; sbx[slot][2] = x2; sbx[slot][3] = y2;
        ssb[slot] = score;
        soidb[slot] = (row - b * NN) * CM1 + (c - 1);
      }
    }
  }
  atomicMax(&smaxs, tmax);  // LDS atomic
  __syncthreads();
  const int n = scnt;
  if (t == 0) {
    sgbase = atomicAdd(&ws_i[CNT_OFF + b], n);
    atomicMax(&ws_i[MAX_OFF + b], smaxs);
  }
  __syncthreads();
  const int gb = sgbase;
  for (int j = t; j < n; j += 256) {
    const int pos = gb + j;
    if (pos < GCAP) {
      reinterpret_cast<float4*>(ws_f + GBOX_OFF)[b * GCAP + pos] =
          make_float4(sbx[j][0], sbx[j][1], sbx[j][2], sbx[j][3]);
      ws_f[GSC_OFF + b * GCAP + pos] = ssb[j];
      ws_i[GOID_OFF + b * GCAP + pos] = soidb[j];
    }
  }
}

// One block per image: LDS histogram -> cutoff -> compact -> bitonic sort by
// (score desc, oid asc) -> single-wave sequential accept scan (no barriers).
__global__ void __launch_bounds__(256) nms_kernel(const int* __restrict__ ws_i,
                                                  const float* __restrict__ ws_f,
                                                  float* __restrict__ out) {
  const int b = blockIdx.x;
  const int t = threadIdx.x;
  __shared__ unsigned long long skey[CAP];   // aliases hist/seg before compact
  __shared__ unsigned int sidx[CAP];         // (label<<16) | slot
  __shared__ float4 bx4[CAP];
  __shared__ float4 selbox[100];
  __shared__ unsigned long long selkey[100];
  __shared__ int sellbl[100];
  __shared__ int bestt;
  __shared__ int cnt2;
  __shared__ int snacc;

  int* hist = (int*)skey;           // 1024 ints (bytes 0..4095)
  int* seg = ((int*)skey) + 1024;   // 256 ints (bytes 4096..5119)

  int M = ws_i[CNT_OFF + b];
  if (M > GCAP) M = GCAP;
  const float maxp1 = __int_as_float(ws_i[MAX_OFF + b]) + 1.0f;
  const float* gsc = ws_f + GSC_OFF + (size_t)b * GCAP;
  const int* goid = ws_i + GOID_OFF + (size_t)b * GCAP;
  const float4* gbox = reinterpret_cast<const float4*>(ws_f + GBOX_OFF) + (size_t)b * GCAP;

  for (int j = t; j < 1024; j += 256) hist[j] = 0;
  if (t == 0) { bestt = 1024; cnt2 = 0; }
  __syncthreads();

  for (int j = t; j < M; j += 256) {
    const float s = gsc[j];
    int bi = (int)(__float_as_uint(s) >> 16) - 15360;
    bi = min(max(bi, 0), 1023);
    atomicAdd(&hist[bi], 1);
  }
  __syncthreads();

  // cutoff: smallest bin tk with count(bins >= tk) <= CAP
  const int h0 = hist[4 * t + 0], h1 = hist[4 * t + 1];
  const int h2 = hist[4 * t + 2], h3 = hist[4 * t + 3];
  seg[t] = h0 + h1 + h2 + h3;
  __syncthreads();
  for (int off = 1; off < 256; off <<= 1) {
    const int v = (t + off < 256) ? seg[t + off] : 0;
    __syncthreads();
    seg[t] += v;
    __syncthreads();
  }
  {
    const int higher = (t < 255) ? seg[t + 1] : 0;
    int A = higher;
    int cnd = 0x7FFFFFFF;
    A += h3; if (A <= CAP) cnd = 4 * t + 3;
    A += h2; if (A <= CAP) cnd = 4 * t + 2;
    A += h1; if (A <= CAP) cnd = 4 * t + 1;
    A += h0; if (A <= CAP) cnd = 4 * t + 0;
    if (cnd != 0x7FFFFFFF) atomicMin(&bestt, cnd);
  }
  __syncthreads();
  const int tk = bestt;
  __syncthreads();   // all reads of hist/seg done before overwrite

  // zero keys (overwrites hist/seg region)
  for (int j = t; j < CAP; j += 256) skey[j] = 0ull;
  __syncthreads();

  // compact kept candidates
  for (int j = t; j < M; j += 256) {
    const float s = gsc[j];
    int bi = (int)(__float_as_uint(s) >> 16) - 15360;
    bi = min(max(bi, 0), 1023);
    if (bi >= tk) {
      const int pos = atomicAdd(&cnt2, 1);  // <= CAP by cutoff construction
      bx4[pos] = gbox[j];
      const int oid = goid[j];
      const int lbl = oid - CM1 * (oid / CM1) + 1;
      skey[pos] = ((unsigned long long)(__float_as_uint(s) | 0x80000000u) << 32) |
                  (unsigned)(0xFFFFFFFFu - (unsigned)oid);
      sidx[pos] = ((unsigned)lbl << 16) | (unsigned)pos;
    }
  }

  // bitonic sort descending by key (dead slots key=0 sink to the end)
  for (int k = 2; k <= CAP; k <<= 1) {
    for (int s = k >> 1; s > 0; s >>= 1) {
      __syncthreads();
      for (int i = t; i < CAP; i += 256) {
        const int ixj = i ^ s;
        if (ixj > i) {
          const bool desc = ((i & k) == 0);
          const unsigned long long a = skey[i];
          const unsigned long long bb = skey[ixj];
          if ((a < bb) == desc) {
            skey[i] = bb; skey[ixj] = a;
            const unsigned tmp = sidx[i]; sidx[i] = sidx[ixj]; sidx[ixj] = tmp;
          }
        }
      }
    }
  }
  __syncthreads();

  // single-wave sequential accept scan (reference NMS semantics)
  if (t < 64) {
    const int lane = t;
    float A0x = 0.f, A0y = 0.f, A0z = 0.f, A0w = 0.f; int L0 = -1;
    float A1x = 0.f, A1y = 0.f, A1z = 0.f, A1w = 0.f; int L1 = -1;
    int nacc = 0;
    unsigned long long key = skey[0];
    unsigned pay = sidx[0];
    for (int j = 0; j < CAP; ++j) {
      if (key == 0ull) break;
      const unsigned long long nkey = (j + 1 < CAP) ? skey[j + 1] : 0ull;
      const unsigned npay = (j + 1 < CAP) ? sidx[j + 1] : 0u;
      const int lbl = (int)(pay >> 16);
      const float4 bb = bx4[pay & 0xFFFFu];
      const float oi = (float)lbl * maxp1;
      const float q0 = bb.x + oi, q1 = bb.y + oi;
      const float q2 = bb.z + oi, q3 = bb.w + oi;
      const float a2 = (q2 - q0) * (q3 - q1);
      bool sup = false;
      if (L0 == lbl) {
        const float n0 = A0x + oi, n1 = A0y + oi, n2 = A0z + oi, n3 = A0w + oi;
        const float a1 = (n2 - n0) * (n3 - n1);
        const float ix1 = fmaxf(n0, q0), iy1 = fmaxf(n1, q1);
        const float ix2 = fminf(n2, q2), iy2 = fminf(n3, q3);
        const float inter = fmaxf(ix2 - ix1, 0.0f) * fmaxf(iy2 - iy1, 0.0f);
        const float iou = inter / ((a1 + a2) - inter);
        sup = (iou > 0.5f);
      }
      if (L1 == lbl) {
        const float n0 = A1x + oi, n1 = A1y + oi, n2 = A1z + oi, n3 = A1w + oi;
        const float a1 = (n2 - n0) * (n3 - n1);
        const float ix1 = fmaxf(n0, q0), iy1 = fmaxf(n1, q1);
        const float ix2 = fminf(n2, q2), iy2 = fminf(n3, q3);
        const float inter = fmaxf(ix2 - ix1, 0.0f) * fmaxf(iy2 - iy1, 0.0f);
        const float iou = inter / ((a1 + a2) - inter);
        sup = sup || (iou > 0.5f);
      }
      if (!__any(sup ? 1 : 0)) {
        if (nacc < 64) {
          if (lane == nacc) { A0x = bb.x; A0y = bb.y; A0z = bb.z; A0w = bb.w; L0 = lbl; }
        } else {
          if (lane == nacc - 64) { A1x = bb.x; A1y = bb.y; A1z = bb.z; A1w = bb.w; L1 = lbl; }
        }
        if (lane == 0) { selbox[nacc] = bb; selkey[nacc] = key; sellbl[nacc] = lbl; }
        nacc++;
        if (nacc == 100) break;
      }
      key = nkey; pay = npay;
    }
    if (lane == 0) snacc = nacc;
  }
  __syncthreads();
  const int nacc = snacc;

  for (int k2 = t; k2 < 100; k2 += 256) {
    float o0 = 0.f, o1 = 0.f, o2 = 0.f, o3 = 0.f, sc = 0.f, lb = 0.f;
    if (k2 < nacc) {
      const float4 v = selbox[k2];
      o0 = v.x; o1 = v.y; o2 = v.z; o3 = v.w;
      sc = __uint_as_float((unsigned)(selkey[k2] >> 32) & 0x7FFFFFFFu);
      lb = (float)sellbl[k2];
    }
    float* ob = out + ((size_t)b * 100 + k2) * 4;
    ob[0] = o0; ob[1] = o1; ob[2] = o2; ob[3] = o3;
    out[NB * 100 * 4 + b * 100 + k2] = sc;
    out[NB * 100 * 4 + NB * 100 + b * 100 + k2] = lb;
  }
}

extern "C" void kernel_launch(void* const* d_in, const int* in_sizes, int n_in,
                              void* d_out, int out_size, void* d_ws, size_t ws_size,
                              hipStream_t stream) {
  const float* logits = (const float*)d_in[0];
  const float* rel = (const float*)d_in[1];
  const float* props = (const float*)d_in[2];
  float* out = (float*)d_out;
  int* ws_i = (int*)d_ws;
  float* ws_f = (float*)d_ws;

  init_kernel<<<1, 256, 0, stream>>>(ws_i);
  cand_kernel<<<NB * BPI, 256, 0, stream>>>(logits, rel, props, ws_i, ws_f);
  nms_kernel<<<NB, 256, 0, stream>>>(ws_i, ws_f, out);
}

// Round 6
// 163.383 us; speedup vs baseline: 4.1009x; 1.7513x over previous
//
#include <hip/hip_runtime.h>
#include <math.h>

#pragma clang fp contract(off)

#define NB 4
#define NN 8000
#define NC 91
#define CM1 90
#define CAP 2048          // outer kept bound (proven sufficient rounds 1-5)
#define ACAP 512          // chunk-A padded size
#define ATHR 448          // chunk-A histogram bound
#define GCAP 65536
#define RPB 16            // rows per block in cand_kernel
#define BPI (NN / RPB)    // 500 blocks per image
#define LCAP 320          // >= RPB*19 (hard bound: <=19 scores>0.05 per row)
#define GWB 16            // wide blocks per image for hist/gather

// ws layout (32-bit words)
#define CNT_OFF 0    // NB valid count
#define MAX_OFF 4    // NB coord-max bits
#define TK_OFF 8     // NB
#define TK2_OFF 12   // NB
#define CNTA_OFF 16  // NB
#define CNTR_OFF 20  // NB
#define HIST_OFF 32  // NB*1024
#define GBOX_OFF 4128                       // NB*GCAP float4
#define GSC_OFF (GBOX_OFF + NB * GCAP * 4)
#define GOID_OFF (GSC_OFF + NB * GCAP)
#define ABOX_OFF (GOID_OFF + NB * GCAP)     // NB*ACAP float4
#define AKEY_OFF (ABOX_OFF + NB * ACAP * 4) // NB*ACAP u64 (2 words each)
#define RBOX_OFF (AKEY_OFF + NB * ACAP * 2) // NB*CAP float4
#define RKEY_OFF (RBOX_OFF + NB * CAP * 4)  // NB*CAP u64

__global__ void init_kernel(int* ws_i) {
  for (int j = threadIdx.x; j < HIST_OFF + NB * 1024; j += 256) ws_i[j] = 0;
}

// UNCHANGED from round 5 (proven ~55us): fused softmax+decode+compact.
__global__ void __launch_bounds__(256) cand_kernel(const float* __restrict__ logits,
                                                   const float* __restrict__ rel,
                                                   const float* __restrict__ props,
                                                   int* __restrict__ ws_i,
                                                   float* __restrict__ ws_f) {
  const int blk = blockIdx.x;
  const int b = blk / BPI;
  const int t = threadIdx.x;
  const int lane = t & 63;
  const int wid = t >> 6;

  __shared__ float sbx[LCAP][4];
  __shared__ float ssb[LCAP];
  __shared__ int soidb[LCAP];
  __shared__ int scnt;
  __shared__ int smaxs;
  __shared__ int sgbase;
  if (t == 0) { scnt = 0; smaxs = 0; }
  __syncthreads();

  int tmax = 0;

  for (int i = 0; i < 4; ++i) {
    const int row = blk * RPB + wid * 4 + i;
    const float* lp = logits + (size_t)row * NC;
    const float l0 = lp[lane];
    const bool hi = (lane + 64 < NC);
    const float l1 = hi ? lp[lane + 64] : -INFINITY;
    float m = fmaxf(l0, l1);
    for (int mm = 32; mm; mm >>= 1) m = fmaxf(m, __shfl_xor(m, mm));
    float sum = expf(l0 - m) + (hi ? expf(l1 - m) : 0.0f);
    for (int mm = 32; mm; mm >>= 1) sum += __shfl_xor(sum, mm);

    const float4 p = reinterpret_cast<const float4*>(props)[row];
    const float w = p.z - p.x, h = p.w - p.y;
    const float cx = p.x + 0.5f * w, cy = p.y + 0.5f * h;

    for (int pp = 0; pp < 2; ++pp) {
      const int c = 1 + lane + 64 * pp;
      bool valid = false;
      float x1 = 0.f, y1 = 0.f, x2 = 0.f, y2 = 0.f, score = 0.f;
      if (c < NC) {
        const float lc = lp[c];
        const float4 r = reinterpret_cast<const float4*>(rel)[(size_t)row * NC + c];
        const float dx = r.x / 10.0f, dy = r.y / 10.0f;
        const float dw = fminf(r.z / 5.0f, 4.135166556742356f);
        const float dh = fminf(r.w / 5.0f, 4.135166556742356f);
        const float pcx = dx * w + cx, pcy = dy * h + cy;
        const float pw = expf(dw) * w, ph = expf(dh) * h;
        x1 = pcx - 0.5f * pw; y1 = pcy - 0.5f * ph;
        x2 = pcx + 0.5f * pw; y2 = pcy + 0.5f * ph;
        x1 = fminf(fmaxf(x1, 0.0f), 1333.0f);
        y1 = fminf(fmaxf(y1, 0.0f), 800.0f);
        x2 = fminf(fmaxf(x2, 0.0f), 1333.0f);
        y2 = fminf(fmaxf(y2, 0.0f), 800.0f);
        score = expf(lc - m) / sum;
        const float localmax = fmaxf(fmaxf(x1, y1), fmaxf(x2, y2));
        tmax = max(tmax, __float_as_int(localmax));
        const float bw = x2 - x1, bh = y2 - y1;
        valid = (score > 0.05f) && (bw >= 0.01f) && (bh >= 0.01f);
      }
      const unsigned long long mk = __ballot(valid);
      if (valid) {
        const int leader = __ffsll(mk) - 1;
        const int rank = __popcll(mk & ((1ull << lane) - 1));
        int basel = 0;
        if (lane == leader) basel = atomicAdd(&scnt, __popcll(mk));
        basel = __shfl(basel, leader);
        const int slot = basel + rank;
        sbx[slot][0] = x1; sbx[slot][1] = y1; sbx[slot][2] = x2; sbx[slot][3] = y2;
        ssb[slot] = score;
        soidb[slot] = (row - b * NN) * CM1 + (c - 1);
      }
    }
  }
  atomicMax(&smaxs, tmax);
  __syncthreads();
  const int n = scnt;
  if (t == 0) {
    sgbase = atomicAdd(&ws_i[CNT_OFF + b], n);
    atomicMax(&ws_i[MAX_OFF + b], smaxs);
  }
  __syncthreads();
  const int gb = sgbase;
  for (int j = t; j < n; j += 256) {
    const int pos = gb + j;
    if (pos < GCAP) {
      reinterpret_cast<float4*>(ws_f + GBOX_OFF)[b * GCAP + pos] =
          make_float4(sbx[j][0], sbx[j][1], sbx[j][2], sbx[j][3]);
      ws_f[GSC_OFF + b * GCAP + pos] = ssb[j];
      ws_i[GOID_OFF + b * GCAP + pos] = soidb[j];
    }
  }
}

// Wide: per-image 1024-bin score histogram (LDS accumulate, global merge).
__global__ void __launch_bounds__(256) hist_kernel(int* __restrict__ ws_i,
                                                   const float* __restrict__ ws_f) {
  const int b = blockIdx.x / GWB, sub = blockIdx.x % GWB;
  const int t = threadIdx.x;
  __shared__ int lh[1024];
  for (int j = t; j < 1024; j += 256) lh[j] = 0;
  __syncthreads();
  int M = ws_i[CNT_OFF + b];
  if (M > GCAP) M = GCAP;
  const float* gsc = ws_f + GSC_OFF + (size_t)b * GCAP;
  for (int j = sub * 256 + t; j < M; j += GWB * 256) {
    int bi = (int)(__float_as_uint(gsc[j]) >> 16) - 15360;
    bi = min(max(bi, 0), 1023);
    atomicAdd(&lh[bi], 1);
  }
  __syncthreads();
  for (int j = t; j < 1024; j += 256)
    if (lh[j]) atomicAdd(&ws_i[HIST_OFF + b * 1024 + j], lh[j]);
}

// Per image: tk = smallest bin with cnt(>=tk) <= CAP; tk2 likewise for ATHR.
__global__ void cutoff_kernel(int* __restrict__ ws_i) {
  const int b = blockIdx.x;
  const int t = threadIdx.x;
  __shared__ int seg[256];
  __shared__ int best1, best2;
  const int* H = ws_i + HIST_OFF + b * 1024;
  const int h0 = H[4 * t + 0], h1 = H[4 * t + 1];
  const int h2 = H[4 * t + 2], h3 = H[4 * t + 3];
  seg[t] = h0 + h1 + h2 + h3;
  if (t == 0) { best1 = 1024; best2 = 1024; }
  __syncthreads();
  for (int off = 1; off < 256; off <<= 1) {
    const int v = (t + off < 256) ? seg[t + off] : 0;
    __syncthreads();
    seg[t] += v;
    __syncthreads();
  }
  const int higher = (t < 255) ? seg[t + 1] : 0;
  {
    int A = higher; int cnd = 0x7FFFFFFF;
    A += h3; if (A <= CAP) cnd = 4 * t + 3;
    A += h2; if (A <= CAP) cnd = 4 * t + 2;
    A += h1; if (A <= CAP) cnd = 4 * t + 1;
    A += h0; if (A <= CAP) cnd = 4 * t + 0;
    if (cnd != 0x7FFFFFFF) atomicMin(&best1, cnd);
  }
  {
    int A = higher; int cnd = 0x7FFFFFFF;
    A += h3; if (A <= ATHR) cnd = 4 * t + 3;
    A += h2; if (A <= ATHR) cnd = 4 * t + 2;
    A += h1; if (A <= ATHR) cnd = 4 * t + 1;
    A += h0; if (A <= ATHR) cnd = 4 * t + 0;
    if (cnd != 0x7FFFFFFF) atomicMin(&best2, cnd);
  }
  __syncthreads();
  if (t == 0) { ws_i[TK_OFF + b] = best1; ws_i[TK2_OFF + b] = best2; }
}

// Wide: split kept candidates into chunk-A (bin>=tk2) and reserve [tk,tk2).
__global__ void __launch_bounds__(256) gather_kernel(int* __restrict__ ws_i,
                                                     float* __restrict__ ws_f) {
  const int b = blockIdx.x / GWB, sub = blockIdx.x % GWB;
  const int t = threadIdx.x;
  const int lane = t & 63;
  int M = ws_i[CNT_OFF + b];
  if (M > GCAP) M = GCAP;
  const int tk = ws_i[TK_OFF + b], tk2 = ws_i[TK2_OFF + b];
  const float* gsc = ws_f + GSC_OFF + (size_t)b * GCAP;
  const int* goid = ws_i + GOID_OFF + (size_t)b * GCAP;
  const float4* gbox = reinterpret_cast<const float4*>(ws_f + GBOX_OFF) + (size_t)b * GCAP;
  float4* abox = reinterpret_cast<float4*>(ws_f + ABOX_OFF) + (size_t)b * ACAP;
  unsigned long long* akey = reinterpret_cast<unsigned long long*>(ws_i + AKEY_OFF) + (size_t)b * ACAP;
  float4* rbox = reinterpret_cast<float4*>(ws_f + RBOX_OFF) + (size_t)b * CAP;
  unsigned long long* rkey = reinterpret_cast<unsigned long long*>(ws_i + RKEY_OFF) + (size_t)b * CAP;

  for (int j = sub * 256 + t; j < M; j += GWB * 256) {
    const float s = gsc[j];
    int bi = (int)(__float_as_uint(s) >> 16) - 15360;
    bi = min(max(bi, 0), 1023);
    const bool inA = (bi >= tk2);
    const bool inR = !inA && (bi >= tk);
    const unsigned long long mA = __ballot(inA);
    if (inA) {
      const int leader = __ffsll(mA) - 1;
      const int rank = __popcll(mA & ((1ull << lane) - 1));
      int basel = 0;
      if (lane == leader) basel = atomicAdd(&ws_i[CNTA_OFF + b], __popcll(mA));
      basel = __shfl(basel, leader);
      const int pos = basel + rank;
      if (pos < ACAP) {
        abox[pos] = gbox[j];
        akey[pos] = ((unsigned long long)(__float_as_uint(s) | 0x80000000u) << 32) |
                    (unsigned)(0xFFFFFFFFu - (unsigned)goid[j]);
      }
    }
    const unsigned long long mR = __ballot(inR);
    if (inR) {
      const int leader = __ffsll(mR) - 1;
      const int rank = __popcll(mR & ((1ull << lane) - 1));
      int basel = 0;
      if (lane == leader) basel = atomicAdd(&ws_i[CNTR_OFF + b], __popcll(mR));
      basel = __shfl(basel, leader);
      const int pos = basel + rank;
      if (pos < CAP) {
        rbox[pos] = gbox[j];
        rkey[pos] = ((unsigned long long)(__float_as_uint(s) | 0x80000000u) << 32) |
                    (unsigned)(0xFFFFFFFFu - (unsigned)goid[j]);
      }
    }
  }
}

// One block per image: rank-sort chunk A in LDS, single-wave sequential accept
// scan; fallback max-extract over reserve if <100 accepts (normally not taken).
__global__ void __launch_bounds__(256) nms_kernel(const int* __restrict__ ws_i,
                                                  const float* __restrict__ ws_f,
                                                  float* __restrict__ out) {
  const int b = blockIdx.x;
  const int t = threadIdx.x;
  const int lane = t & 63;
  __shared__ __align__(16) char sm[57344];
  unsigned long long* akey = (unsigned long long*)sm;            // 512 u64
  float4* abox = (float4*)(sm + 4096);                           // 512 f4
  unsigned long long* skeyS = (unsigned long long*)(sm + 12288); // 512 u64
  float4* sboxS = (float4*)(sm + 16384);                         // 512 f4
  int* slblS = (int*)(sm + 24576);                               // 512 int
  // fallback aliases (used strictly after chunk phase):
  unsigned long long* rkeyS = (unsigned long long*)sm;           // 2048 u64
  float4* rboxS = (float4*)(sm + 16384);                         // 2048 f4
  int* rlblS = (int*)(sm + 49152);                               // 2048 int
  __shared__ float4 selbox[100];
  __shared__ unsigned long long selkey[100];
  __shared__ int sellbl[100];
  __shared__ int snacc;
  __shared__ int sneed;

  const int nA = min(ws_i[CNTA_OFF + b], ACAP);
  const int nR = min(ws_i[CNTR_OFF + b], CAP);
  const float maxp1 = __int_as_float(ws_i[MAX_OFF + b]) + 1.0f;
  const float4* gA = reinterpret_cast<const float4*>(ws_f + ABOX_OFF) + (size_t)b * ACAP;
  const unsigned long long* gAk =
      reinterpret_cast<const unsigned long long*>(ws_i + AKEY_OFF) + (size_t)b * ACAP;

  for (int j = t; j < ACAP; j += 256) {
    akey[j] = (j < nA) ? gAk[j] : 0ull;
    if (j < nA) abox[j] = gA[j];
    skeyS[j] = 0ull;
  }
  __syncthreads();

  // exact rank-sort (keys unique): rank = #{keys greater}
#pragma unroll
  for (int rr = 0; rr < 2; ++rr) {
    const int j = t + rr * 256;
    const unsigned long long kj = akey[j];
    if (kj != 0ull) {
      int rank = 0;
      for (int i = 0; i < ACAP; ++i) rank += (akey[i] > kj) ? 1 : 0;
      skeyS[rank] = kj;
      sboxS[rank] = abox[j];
      const unsigned oid = 0xFFFFFFFFu - (unsigned)(kj & 0xFFFFFFFFull);
      slblS[rank] = (int)(oid % 90u) + 1;
    }
  }
  __syncthreads();

  // accepted state (wave 0): lane L holds accepted #L and #(64+L)
  float A0x = 0.f, A0y = 0.f, A0z = 0.f, A0w = 0.f; int L0 = -1;
  float A1x = 0.f, A1y = 0.f, A1z = 0.f, A1w = 0.f; int L1 = -1;
  int nacc = 0;

  if (t < 64) {
    unsigned long long key = skeyS[0];
    float4 bb = sboxS[0];
    int lbl = slblS[0];
    for (int j = 0; j < ACAP; ++j) {
      if (key == 0ull) break;
      const int jn = (j + 1 < ACAP) ? j + 1 : j;
      const unsigned long long nk = (j + 1 < ACAP) ? skeyS[j + 1] : 0ull;
      const float4 nbb = sboxS[jn];
      const int nlb = slblS[jn];
      const float oi = (float)lbl * maxp1;
      const float q0 = bb.x + oi, q1 = bb.y + oi;
      const float q2 = bb.z + oi, q3 = bb.w + oi;
      const float a2 = (q2 - q0) * (q3 - q1);
      bool sup = false;
      if (L0 == lbl) {
        const float n0 = A0x + oi, n1 = A0y + oi, n2 = A0z + oi, n3 = A0w + oi;
        const float a1 = (n2 - n0) * (n3 - n1);
        const float ix1 = fmaxf(n0, q0), iy1 = fmaxf(n1, q1);
        const float ix2 = fminf(n2, q2), iy2 = fminf(n3, q3);
        const float inter = fmaxf(ix2 - ix1, 0.0f) * fmaxf(iy2 - iy1, 0.0f);
        const float iou = inter / ((a1 + a2) - inter);
        sup = (iou > 0.5f);
      }
      if (L1 == lbl) {
        const float n0 = A1x + oi, n1 = A1y + oi, n2 = A1z + oi, n3 = A1w + oi;
        const float a1 = (n2 - n0) * (n3 - n1);
        const float ix1 = fmaxf(n0, q0), iy1 = fmaxf(n1, q1);
        const float ix2 = fminf(n2, q2), iy2 = fminf(n3, q3);
        const float inter = fmaxf(ix2 - ix1, 0.0f) * fmaxf(iy2 - iy1, 0.0f);
        const float iou = inter / ((a1 + a2) - inter);
        sup = sup || (iou > 0.5f);
      }
      if (!__any(sup ? 1 : 0)) {
        if (nacc < 64) {
          if (lane == nacc) { A0x = bb.x; A0y = bb.y; A0z = bb.z; A0w = bb.w; L0 = lbl; }
        } else {
          if (lane == nacc - 64) { A1x = bb.x; A1y = bb.y; A1z = bb.z; A1w = bb.w; L1 = lbl; }
        }
        if (lane == 0) { selbox[nacc] = bb; selkey[nacc] = key; sellbl[nacc] = lbl; }
        ++nacc;
        if (nacc == 100) break;
      }
      key = nk; bb = nbb; lbl = nlb;
    }
    if (lane == 0) { snacc = nacc; sneed = (nacc < 100 && nR > 0) ? 1 : 0; }
  }
  __syncthreads();

  if (sneed) {  // normally never taken: continue over reserve in exact order
    const float4* gR = reinterpret_cast<const float4*>(ws_f + RBOX_OFF) + (size_t)b * CAP;
    const unsigned long long* gRk =
        reinterpret_cast<const unsigned long long*>(ws_i + RKEY_OFF) + (size_t)b * CAP;
    for (int j = t; j < CAP; j += 256) {
      const unsigned long long k = (j < nR) ? gRk[j] : 0ull;
      rkeyS[j] = k;
      if (j < nR) {
        rboxS[j] = gR[j];
        const unsigned oid = 0xFFFFFFFFu - (unsigned)(k & 0xFFFFFFFFull);
        rlblS[j] = (int)(oid % 90u) + 1;
      }
    }
    __syncthreads();
    if (t < 64) {
      while (nacc < 100) {
        unsigned long long mk = 0ull; int mi = 0;
        for (int j = lane; j < nR; j += 64) {
          const unsigned long long k = rkeyS[j];
          if (k > mk) { mk = k; mi = j; }
        }
        for (int mm = 1; mm < 64; mm <<= 1) {
          const unsigned long long ok = __shfl_xor(mk, mm);
          const int om = __shfl_xor(mi, mm);
          if (ok > mk) { mk = ok; mi = om; }
        }
        if (mk == 0ull) break;
        if (lane == 0) rkeyS[mi] = 0ull;
        __asm__ volatile("s_waitcnt lgkmcnt(0)" ::: "memory");
        const int lbl = rlblS[mi];
        const float4 bb = rboxS[mi];
        const float oi = (float)lbl * maxp1;
        const float q0 = bb.x + oi, q1 = bb.y + oi;
        const float q2 = bb.z + oi, q3 = bb.w + oi;
        const float a2 = (q2 - q0) * (q3 - q1);
        bool sup = false;
        if (L0 == lbl) {
          const float n0 = A0x + oi, n1 = A0y + oi, n2 = A0z + oi, n3 = A0w + oi;
          const float a1 = (n2 - n0) * (n3 - n1);
          const float ix1 = fmaxf(n0, q0), iy1 = fmaxf(n1, q1);
          const float ix2 = fminf(n2, q2), iy2 = fminf(n3, q3);
          const float inter = fmaxf(ix2 - ix1, 0.0f) * fmaxf(iy2 - iy1, 0.0f);
          const float iou = inter / ((a1 + a2) - inter);
          sup = (iou > 0.5f);
        }
        if (L1 == lbl) {
          const float n0 = A1x + oi, n1 = A1y + oi, n2 = A1z + oi, n3 = A1w + oi;
          const float a1 = (n2 - n0) * (n3 - n1);
          const float ix1 = fmaxf(n0, q0), iy1 = fmaxf(n1, q1);
          const float ix2 = fminf(n2, q2), iy2 = fminf(n3, q3);
          const float inter = fmaxf(ix2 - ix1, 0.0f) * fmaxf(iy2 - iy1, 0.0f);
          const float iou = inter / ((a1 + a2) - inter);
          sup = sup || (iou > 0.5f);
        }
        if (!__any(sup ? 1 : 0)) {
          if (nacc < 64) {
            if (lane == nacc) { A0x = bb.x; A0y = bb.y; A0z = bb.z; A0w = bb.w; L0 = lbl; }
          } else {
            if (lane == nacc - 64) { A1x = bb.x; A1y = bb.y; A1z = bb.z; A1w = bb.w; L1 = lbl; }
          }
          if (lane == 0) { selbox[nacc] = bb; selkey[nacc] = mk; sellbl[nacc] = lbl; }
          ++nacc;
        }
      }
      if (lane == 0) snacc = nacc;
    }
    __syncthreads();
  }

  const int nf = snacc;
  for (int k2 = t; k2 < 100; k2 += 256) {
    float o0 = 0.f, o1 = 0.f, o2 = 0.f, o3 = 0.f, sc = 0.f, lb = 0.f;
    if (k2 < nf) {
      const float4 v = selbox[k2];
      o0 = v.x; o1 = v.y; o2 = v.z; o3 = v.w;
      sc = __uint_as_float((unsigned)(selkey[k2] >> 32) & 0x7FFFFFFFu);
      lb = (float)sellbl[k2];
    }
    float* ob = out + ((size_t)b * 100 + k2) * 4;
    ob[0] = o0; ob[1] = o1; ob[2] = o2; ob[3] = o3;
    out[NB * 100 * 4 + b * 100 + k2] = sc;
    out[NB * 100 * 4 + NB * 100 + b * 100 + k2] = lb;
  }
}

extern "C" void kernel_launch(void* const* d_in, const int* in_sizes, int n_in,
                              void* d_out, int out_size, void* d_ws, size_t ws_size,
                              hipStream_t stream) {
  const float* logits = (const float*)d_in[0];
  const float* rel = (const float*)d_in[1];
  const float* props = (const float*)d_in[2];
  float* out = (float*)d_out;
  int* ws_i = (int*)d_ws;
  float* ws_f = (float*)d_ws;

  init_kernel<<<1, 256, 0, stream>>>(ws_i);
  cand_kernel<<<NB * BPI, 256, 0, stream>>>(logits, rel, props, ws_i, ws_f);
  hist_kernel<<<NB * GWB, 256, 0, stream>>>(ws_i, ws_f);
  cutoff_kernel<<<NB, 256, 0, stream>>>(ws_i);
  gather_kernel<<<NB * GWB, 256, 0, stream>>>(ws_i, ws_f);
  nms_kernel<<<NB, 256, 0, stream>>>(ws_i, ws_f, out);
}

// Round 7
// 133.226 us; speedup vs baseline: 5.0292x; 1.2264x over previous
//
#include <hip/hip_runtime.h>
#include <math.h>

#pragma clang fp contract(off)

#define NB 4
#define NN 8000
#define NC 91
#define CM1 90
#define CAP 2048          // outer kept bound (proven sufficient rounds 1-6)
#define ACAP 512          // chunk-A padded size
#define ATHR 448          // chunk-A histogram bound
#define GCAP 65536
#define RPB 64            // rows per block in cand_kernel
#define BPI (NN / RPB)    // 125 blocks per image
#define LCAP 1216         // = RPB*19 (hard bound: <=19 scores>0.05 per row)
#define GWB 16            // wide blocks per image for gather

// ws layout (32-bit words)
#define CNT_OFF 0    // NB valid count
#define MAX_OFF 4    // NB coord-max bits
#define CNTA_OFF 16  // NB
#define CNTR_OFF 20  // NB
#define HIST_OFF 32  // NB*1024
#define GBOX_OFF 4128                       // NB*GCAP float4
#define GSC_OFF (GBOX_OFF + NB * GCAP * 4)
#define GOID_OFF (GSC_OFF + NB * GCAP)
#define ABOX_OFF (GOID_OFF + NB * GCAP)     // NB*ACAP float4
#define AKEY_OFF (ABOX_OFF + NB * ACAP * 4) // NB*ACAP u64 (2 words each)
#define RBOX_OFF (AKEY_OFF + NB * ACAP * 2) // NB*CAP float4
#define RKEY_OFF (RBOX_OFF + NB * CAP * 4)  // NB*CAP u64

__global__ void init_kernel(int* ws_i) {
  for (int j = threadIdx.x; j < HIST_OFF + NB * 1024; j += 256) ws_i[j] = 0;
}

// 16 lanes per row: softmax tree folds (k,k+64),(k,k+32),(k,k+16) in-register,
// (k,k+8..1) via 4 shfl_xor — pairwise identical to the passing tree.
// Fused: decode + validity + LDS hist + per-image compaction.
__global__ void __launch_bounds__(256) cand_kernel(const float* __restrict__ logits,
                                                   const float* __restrict__ rel,
                                                   const float* __restrict__ props,
                                                   int* __restrict__ ws_i,
                                                   float* __restrict__ ws_f) {
  const int blk = blockIdx.x;
  const int b = blk / BPI;
  const int ib = blk - b * BPI;
  const int t = threadIdx.x;
  const int L = t & 15;      // lane within 16-lane row group
  const int grp = t >> 4;    // 0..15

  __shared__ float sbx[LCAP][4];
  __shared__ float ssb[LCAP];
  __shared__ int soidb[LCAP];
  __shared__ int lhist[1024];
  __shared__ int scnt;
  __shared__ int smaxs;
  __shared__ int sgbase;
  for (int j = t; j < 1024; j += 256) lhist[j] = 0;
  if (t == 0) { scnt = 0; smaxs = 0; }
  __syncthreads();

  int tmax = 0;  // thread-local coord max (float bits; coords >= 0)

  for (int i = 0; i < 4; ++i) {
    const int row = b * NN + ib * RPB + i * 16 + grp;
    const float* lp = logits + (size_t)row * NC;

    float lv[6];
#pragma unroll
    for (int j = 0; j < 6; ++j) {
      const int k = L + 16 * j;
      lv[j] = (k < NC) ? lp[k] : -INFINITY;
    }
    // max: tree (k,k+64),(k,k+32),(k,k+16) in-register (lv[6],lv[7] = -inf)
    float tm0 = fmax(lv[0], lv[4]), tm1 = fmax(lv[1], lv[5]);
    float tm2 = lv[2], tm3 = lv[3];
    float um0 = fmax(tm0, tm2), um1 = fmax(tm1, tm3);
    float m = fmax(um0, um1);
    m = fmaxf(m, __shfl_xor(m, 8));
    m = fmaxf(m, __shfl_xor(m, 4));
    m = fmaxf(m, __shfl_xor(m, 2));
    m = fmaxf(m, __shfl_xor(m, 1));

    float ev[6];
#pragma unroll
    for (int j = 0; j < 6; ++j) {
      const int k = L + 16 * j;
      ev[j] = (k < NC) ? expf(lv[j] - m) : 0.0f;
    }
    float ts0 = ev[0] + ev[4], ts1 = ev[1] + ev[5];
    float ts2 = ev[2], ts3 = ev[3];
    float us0 = ts0 + ts2, us1 = ts1 + ts3;
    float sum = us0 + us1;
    sum += __shfl_xor(sum, 8);
    sum += __shfl_xor(sum, 4);
    sum += __shfl_xor(sum, 2);
    sum += __shfl_xor(sum, 1);

    const float4 p = reinterpret_cast<const float4*>(props)[row];
    const float w = p.z - p.x, h = p.w - p.y;
    const float cx = p.x + 0.5f * w, cy = p.y + 0.5f * h;

#pragma unroll
    for (int j = 0; j < 6; ++j) {
      const int c = L + 16 * j;
      if (c >= 1 && c < NC) {
        const float4 r = reinterpret_cast<const float4*>(rel)[(size_t)row * NC + c];
        const float dx = r.x / 10.0f, dy = r.y / 10.0f;
        const float dw = fminf(r.z / 5.0f, 4.135166556742356f);
        const float dh = fminf(r.w / 5.0f, 4.135166556742356f);
        const float pcx = dx * w + cx, pcy = dy * h + cy;
        const float pw = expf(dw) * w, ph = expf(dh) * h;
        float x1 = pcx - 0.5f * pw, y1 = pcy - 0.5f * ph;
        float x2 = pcx + 0.5f * pw, y2 = pcy + 0.5f * ph;
        x1 = fminf(fmaxf(x1, 0.0f), 1333.0f);
        y1 = fminf(fmaxf(y1, 0.0f), 800.0f);
        x2 = fminf(fmaxf(x2, 0.0f), 1333.0f);
        y2 = fminf(fmaxf(y2, 0.0f), 800.0f);
        const float score = ev[j] / sum;
        const float localmax = fmaxf(fmaxf(x1, y1), fmaxf(x2, y2));
        tmax = max(tmax, __float_as_int(localmax));
        const float bw = x2 - x1, bh = y2 - y1;
        if ((score > 0.05f) && (bw >= 0.01f) && (bh >= 0.01f)) {
          const int slot = atomicAdd(&scnt, 1);  // LDS; bounded by LCAP
          sbx[slot][0] = x1; sbx[slot][1] = y1;
          sbx[slot][2] = x2; sbx[slot][3] = y2;
          ssb[slot] = score;
          soidb[slot] = (row - b * NN) * CM1 + (c - 1);
          int bi = (int)(__float_as_uint(score) >> 16) - 15360;
          bi = min(max(bi, 0), 1023);
          atomicAdd(&lhist[bi], 1);
        }
      }
    }
  }
  atomicMax(&smaxs, tmax);
  __syncthreads();
  const int n = scnt;
  if (t == 0) {
    sgbase = atomicAdd(&ws_i[CNT_OFF + b], n);
    atomicMax(&ws_i[MAX_OFF + b], smaxs);
  }
  __syncthreads();
  const int gb = sgbase;
  for (int j = t; j < n; j += 256) {
    const int pos = gb + j;
    if (pos < GCAP) {
      reinterpret_cast<float4*>(ws_f + GBOX_OFF)[b * GCAP + pos] =
          make_float4(sbx[j][0], sbx[j][1], sbx[j][2], sbx[j][3]);
      ws_f[GSC_OFF + b * GCAP + pos] = ssb[j];
      ws_i[GOID_OFF + b * GCAP + pos] = soidb[j];
    }
  }
  for (int j = t; j < 1024; j += 256) {
    const int v = lhist[j];
    if (v) atomicAdd(&ws_i[HIST_OFF + b * 1024 + j], v);
  }
}

// Wide, with fused cutoff: each block recomputes tk (cnt(>=tk)<=CAP) and tk2
// (cnt(>=tk2)<=ATHR) from the global hist, then splits kept candidates into
// chunk-A (bin>=tk2) and reserve [tk,tk2).
__global__ void __launch_bounds__(256) gather_kernel(int* __restrict__ ws_i,
                                                     float* __restrict__ ws_f) {
  const int b = blockIdx.x / GWB, sub = blockIdx.x % GWB;
  const int t = threadIdx.x;
  const int lane = t & 63;
  __shared__ int seg[256];
  __shared__ int best1, best2;

  const int* H = ws_i + HIST_OFF + b * 1024;
  const int h0 = H[4 * t + 0], h1 = H[4 * t + 1];
  const int h2 = H[4 * t + 2], h3 = H[4 * t + 3];
  seg[t] = h0 + h1 + h2 + h3;
  if (t == 0) { best1 = 1024; best2 = 1024; }
  __syncthreads();
  for (int off = 1; off < 256; off <<= 1) {
    const int v = (t + off < 256) ? seg[t + off] : 0;
    __syncthreads();
    seg[t] += v;
    __syncthreads();
  }
  const int higher = (t < 255) ? seg[t + 1] : 0;
  {
    int A = higher; int cnd = 0x7FFFFFFF;
    A += h3; if (A <= CAP) cnd = 4 * t + 3;
    A += h2; if (A <= CAP) cnd = 4 * t + 2;
    A += h1; if (A <= CAP) cnd = 4 * t + 1;
    A += h0; if (A <= CAP) cnd = 4 * t + 0;
    if (cnd != 0x7FFFFFFF) atomicMin(&best1, cnd);
  }
  {
    int A = higher; int cnd = 0x7FFFFFFF;
    A += h3; if (A <= ATHR) cnd = 4 * t + 3;
    A += h2; if (A <= ATHR) cnd = 4 * t + 2;
    A += h1; if (A <= ATHR) cnd = 4 * t + 1;
    A += h0; if (A <= ATHR) cnd = 4 * t + 0;
    if (cnd != 0x7FFFFFFF) atomicMin(&best2, cnd);
  }
  __syncthreads();
  const int tk = best1, tk2 = best2;

  int M = ws_i[CNT_OFF + b];
  if (M > GCAP) M = GCAP;
  const float* gsc = ws_f + GSC_OFF + (size_t)b * GCAP;
  const int* goid = ws_i + GOID_OFF + (size_t)b * GCAP;
  const float4* gbox = reinterpret_cast<const float4*>(ws_f + GBOX_OFF) + (size_t)b * GCAP;
  float4* abox = reinterpret_cast<float4*>(ws_f + ABOX_OFF) + (size_t)b * ACAP;
  unsigned long long* akey = reinterpret_cast<unsigned long long*>(ws_i + AKEY_OFF) + (size_t)b * ACAP;
  float4* rbox = reinterpret_cast<float4*>(ws_f + RBOX_OFF) + (size_t)b * CAP;
  unsigned long long* rkey = reinterpret_cast<unsigned long long*>(ws_i + RKEY_OFF) + (size_t)b * CAP;

  for (int j = sub * 256 + t; j < M; j += GWB * 256) {
    const float s = gsc[j];
    int bi = (int)(__float_as_uint(s) >> 16) - 15360;
    bi = min(max(bi, 0), 1023);
    const bool inA = (bi >= tk2);
    const bool inR = !inA && (bi >= tk);
    const unsigned long long mA = __ballot(inA);
    if (inA) {
      const int leader = __ffsll(mA) - 1;
      const int rank = __popcll(mA & ((1ull << lane) - 1));
      int basel = 0;
      if (lane == leader) basel = atomicAdd(&ws_i[CNTA_OFF + b], __popcll(mA));
      basel = __shfl(basel, leader);
      const int pos = basel + rank;
      if (pos < ACAP) {
        abox[pos] = gbox[j];
        akey[pos] = ((unsigned long long)(__float_as_uint(s) | 0x80000000u) << 32) |
                    (unsigned)(0xFFFFFFFFu - (unsigned)goid[j]);
      }
    }
    const unsigned long long mR = __ballot(inR);
    if (inR) {
      const int leader = __ffsll(mR) - 1;
      const int rank = __popcll(mR & ((1ull << lane) - 1));
      int basel = 0;
      if (lane == leader) basel = atomicAdd(&ws_i[CNTR_OFF + b], __popcll(mR));
      basel = __shfl(basel, leader);
      const int pos = basel + rank;
      if (pos < CAP) {
        rbox[pos] = gbox[j];
        rkey[pos] = ((unsigned long long)(__float_as_uint(s) | 0x80000000u) << 32) |
                    (unsigned)(0xFFFFFFFFu - (unsigned)goid[j]);
      }
    }
  }
}

// One block per image: rank-sort chunk A in LDS, single-wave sequential accept
// scan; fallback max-extract over reserve if <100 accepts (normally not taken).
__global__ void __launch_bounds__(256) nms_kernel(const int* __restrict__ ws_i,
                                                  const float* __restrict__ ws_f,
                                                  float* __restrict__ out) {
  const int b = blockIdx.x;
  const int t = threadIdx.x;
  const int lane = t & 63;
  __shared__ __align__(16) char sm[57344];
  unsigned long long* akey = (unsigned long long*)sm;            // 512 u64
  float4* abox = (float4*)(sm + 4096);                           // 512 f4
  unsigned long long* skeyS = (unsigned long long*)(sm + 12288); // 512 u64
  float4* sboxS = (float4*)(sm + 16384);                         // 512 f4
  int* slblS = (int*)(sm + 24576);                               // 512 int
  unsigned long long* rkeyS = (unsigned long long*)sm;           // 2048 u64 (alias)
  float4* rboxS = (float4*)(sm + 16384);                         // 2048 f4 (alias)
  int* rlblS = (int*)(sm + 49152);                               // 2048 int (alias)
  __shared__ float4 selbox[100];
  __shared__ unsigned long long selkey[100];
  __shared__ int sellbl[100];
  __shared__ int snacc;
  __shared__ int sneed;

  const int nA = min(ws_i[CNTA_OFF + b], ACAP);
  const int nR = min(ws_i[CNTR_OFF + b], CAP);
  const float maxp1 = __int_as_float(ws_i[MAX_OFF + b]) + 1.0f;
  const float4* gA = reinterpret_cast<const float4*>(ws_f + ABOX_OFF) + (size_t)b * ACAP;
  const unsigned long long* gAk =
      reinterpret_cast<const unsigned long long*>(ws_i + AKEY_OFF) + (size_t)b * ACAP;

  for (int j = t; j < ACAP; j += 256) {
    akey[j] = (j < nA) ? gAk[j] : 0ull;
    if (j < nA) abox[j] = gA[j];
    skeyS[j] = 0ull;
  }
  __syncthreads();

#pragma unroll
  for (int rr = 0; rr < 2; ++rr) {
    const int j = t + rr * 256;
    const unsigned long long kj = akey[j];
    if (kj != 0ull) {
      int rank = 0;
      for (int i = 0; i < ACAP; ++i) rank += (akey[i] > kj) ? 1 : 0;
      skeyS[rank] = kj;
      sboxS[rank] = abox[j];
      const unsigned oid = 0xFFFFFFFFu - (unsigned)(kj & 0xFFFFFFFFull);
      slblS[rank] = (int)(oid % 90u) + 1;
    }
  }
  __syncthreads();

  float A0x = 0.f, A0y = 0.f, A0z = 0.f, A0w = 0.f; int L0 = -1;
  float A1x = 0.f, A1y = 0.f, A1z = 0.f, A1w = 0.f; int L1 = -1;
  int nacc = 0;

  if (t < 64) {
    unsigned long long key = skeyS[0];
    float4 bb = sboxS[0];
    int lbl = slblS[0];
    for (int j = 0; j < ACAP; ++j) {
      if (key == 0ull) break;
      const int jn = (j + 1 < ACAP) ? j + 1 : j;
      const unsigned long long nk = (j + 1 < ACAP) ? skeyS[j + 1] : 0ull;
      const float4 nbb = sboxS[jn];
      const int nlb = slblS[jn];
      const float oi = (float)lbl * maxp1;
      const float q0 = bb.x + oi, q1 = bb.y + oi;
      const float q2 = bb.z + oi, q3 = bb.w + oi;
      const float a2 = (q2 - q0) * (q3 - q1);
      bool sup = false;
      if (L0 == lbl) {
        const float n0 = A0x + oi, n1 = A0y + oi, n2 = A0z + oi, n3 = A0w + oi;
        const float a1 = (n2 - n0) * (n3 - n1);
        const float ix1 = fmaxf(n0, q0), iy1 = fmaxf(n1, q1);
        const float ix2 = fminf(n2, q2), iy2 = fminf(n3, q3);
        const float inter = fmaxf(ix2 - ix1, 0.0f) * fmaxf(iy2 - iy1, 0.0f);
        const float iou = inter / ((a1 + a2) - inter);
        sup = (iou > 0.5f);
      }
      if (L1 == lbl) {
        const float n0 = A1x + oi, n1 = A1y + oi, n2 = A1z + oi, n3 = A1w + oi;
        const float a1 = (n2 - n0) * (n3 - n1);
        const float ix1 = fmaxf(n0, q0), iy1 = fmaxf(n1, q1);
        const float ix2 = fminf(n2, q2), iy2 = fminf(n3, q3);
        const float inter = fmaxf(ix2 - ix1, 0.0f) * fmaxf(iy2 - iy1, 0.0f);
        const float iou = inter / ((a1 + a2) - inter);
        sup = sup || (iou > 0.5f);
      }
      if (!__any(sup ? 1 : 0)) {
        if (nacc < 64) {
          if (lane == nacc) { A0x = bb.x; A0y = bb.y; A0z = bb.z; A0w = bb.w; L0 = lbl; }
        } else {
          if (lane == nacc - 64) { A1x = bb.x; A1y = bb.y; A1z = bb.z; A1w = bb.w; L1 = lbl; }
        }
        if (lane == 0) { selbox[nacc] = bb; selkey[nacc] = key; sellbl[nacc] = lbl; }
        ++nacc;
        if (nacc == 100) break;
      }
      key = nk; bb = nbb; lbl = nlb;
    }
    if (lane == 0) { snacc = nacc; sneed = (nacc < 100 && nR > 0) ? 1 : 0; }
  }
  __syncthreads();

  if (sneed) {  // normally never taken: continue over reserve in exact order
    const float4* gR = reinterpret_cast<const float4*>(ws_f + RBOX_OFF) + (size_t)b * CAP;
    const unsigned long long* gRk =
        reinterpret_cast<const unsigned long long*>(ws_i + RKEY_OFF) + (size_t)b * CAP;
    for (int j = t; j < CAP; j += 256) {
      const unsigned long long k = (j < nR) ? gRk[j] : 0ull;
      rkeyS[j] = k;
      if (j < nR) {
        rboxS[j] = gR[j];
        const unsigned oid = 0xFFFFFFFFu - (unsigned)(k & 0xFFFFFFFFull);
        rlblS[j] = (int)(oid % 90u) + 1;
      }
    }
    __syncthreads();
    if (t < 64) {
      while (nacc < 100) {
        unsigned long long mk = 0ull; int mi = 0;
        for (int j = lane; j < nR; j += 64) {
          const unsigned long long k = rkeyS[j];
          if (k > mk) { mk = k; mi = j; }
        }
        for (int mm = 1; mm < 64; mm <<= 1) {
          const unsigned long long ok = __shfl_xor(mk, mm);
          const int om = __shfl_xor(mi, mm);
          if (ok > mk) { mk = ok; mi = om; }
        }
        if (mk == 0ull) break;
        if (lane == 0) rkeyS[mi] = 0ull;
        __asm__ volatile("s_waitcnt lgkmcnt(0)" ::: "memory");
        const int lbl = rlblS[mi];
        const float4 bb = rboxS[mi];
        const float oi = (float)lbl * maxp1;
        const float q0 = bb.x + oi, q1 = bb.y + oi;
        const float q2 = bb.z + oi, q3 = bb.w + oi;
        const float a2 = (q2 - q0) * (q3 - q1);
        bool sup = false;
        if (L0 == lbl) {
          const float n0 = A0x + oi, n1 = A0y + oi, n2 = A0z + oi, n3 = A0w + oi;
          const float a1 = (n2 - n0) * (n3 - n1);
          const float ix1 = fmaxf(n0, q0), iy1 = fmaxf(n1, q1);
          const float ix2 = fminf(n2, q2), iy2 = fminf(n3, q3);
          const float inter = fmaxf(ix2 - ix1, 0.0f) * fmaxf(iy2 - iy1, 0.0f);
          const float iou = inter / ((a1 + a2) - inter);
          sup = (iou > 0.5f);
        }
        if (L1 == lbl) {
          const float n0 = A1x + oi, n1 = A1y + oi, n2 = A1z + oi, n3 = A1w + oi;
          const float a1 = (n2 - n0) * (n3 - n1);
          const float ix1 = fmaxf(n0, q0), iy1 = fmaxf(n1, q1);
          const float ix2 = fminf(n2, q2), iy2 = fminf(n3, q3);
          const float inter = fmaxf(ix2 - ix1, 0.0f) * fmaxf(iy2 - iy1, 0.0f);
          const float iou = inter / ((a1 + a2) - inter);
          sup = sup || (iou > 0.5f);
        }
        if (!__any(sup ? 1 : 0)) {
          if (nacc < 64) {
            if (lane == nacc) { A0x = bb.x; A0y = bb.y; A0z = bb.z; A0w = bb.w; L0 = lbl; }
          } else {
            if (lane == nacc - 64) { A1x = bb.x; A1y = bb.y; A1z = bb.z; A1w = bb.w; L1 = lbl; }
          }
          if (lane == 0) { selbox[nacc] = bb; selkey[nacc] = mk; sellbl[nacc] = lbl; }
          ++nacc;
        }
      }
      if (lane == 0) snacc = nacc;
    }
    __syncthreads();
  }

  const int nf = snacc;
  for (int k2 = t; k2 < 100; k2 += 256) {
    float o0 = 0.f, o1 = 0.f, o2 = 0.f, o3 = 0.f, sc = 0.f, lb = 0.f;
    if (k2 < nf) {
      const float4 v = selbox[k2];
      o0 = v.x; o1 = v.y; o2 = v.z; o3 = v.w;
      sc = __uint_as_float((unsigned)(selkey[k2] >> 32) & 0x7FFFFFFFu);
      lb = (float)sellbl[k2];
    }
    float* ob = out + ((size_t)b * 100 + k2) * 4;
    ob[0] = o0; ob[1] = o1; ob[2] = o2; ob[3] = o3;
    out[NB * 100 * 4 + b * 100 + k2] = sc;
    out[NB * 100 * 4 + NB * 100 + b * 100 + k2] = lb;
  }
}

extern "C" void kernel_launch(void* const* d_in, const int* in_sizes, int n_in,
                              void* d_out, int out_size, void* d_ws, size_t ws_size,
                              hipStream_t stream) {
  const float* logits = (const float*)d_in[0];
  const float* rel = (const float*)d_in[1];
  const float* props = (const float*)d_in[2];
  float* out = (float*)d_out;
  int* ws_i = (int*)d_ws;
  float* ws_f = (float*)d_ws;

  init_kernel<<<17, 256, 0, stream>>>(ws_i);
  cand_kernel<<<NB * BPI, 256, 0, stream>>>(logits, rel, props, ws_i, ws_f);
  gather_kernel<<<NB * GWB, 256, 0, stream>>>(ws_i, ws_f);
  nms_kernel<<<NB, 256, 0, stream>>>(ws_i, ws_f, out);
}

// Round 8
// 100.671 us; speedup vs baseline: 6.6556x; 1.3234x over previous
//
#include <hip/hip_runtime.h>
#include <math.h>

#pragma clang fp contract(off)

#define NB 4
#define NN 8000
#define NC 91
#define CM1 90
#define CAP 2048          // outer kept bound (proven sufficient rounds 1-7)
#define ACAP 512          // chunk-A padded size
#define ATHR 448          // chunk-A histogram bound
#define GCAP 65536
#define RPB 64            // rows per block in cand_kernel
#define BPI (NN / RPB)    // 125 blocks per image
#define LCAP 1216         // = RPB*19 (hard bound: <=19 scores>0.05 per row)
#define GWB 16            // wide blocks per image for gather

// ws layout (32-bit words)
#define CNT_OFF 0    // NB valid count
#define MAX_OFF 4    // NB coord-max bits
#define CNTA_OFF 16  // NB
#define CNTR_OFF 20  // NB
#define HIST_OFF 32  // NB*1024
#define GBOX_OFF 4128                       // NB*GCAP float4
#define GSC_OFF (GBOX_OFF + NB * GCAP * 4)
#define GOID_OFF (GSC_OFF + NB * GCAP)
#define ABOX_OFF (GOID_OFF + NB * GCAP)     // NB*ACAP float4
#define AKEY_OFF (ABOX_OFF + NB * ACAP * 4) // NB*ACAP u64 (2 words each)
#define RBOX_OFF (AKEY_OFF + NB * ACAP * 2) // NB*CAP float4
#define RKEY_OFF (RBOX_OFF + NB * CAP * 4)  // NB*CAP u64

__global__ void init_kernel(int* ws_i) {
  for (int j = threadIdx.x; j < HIST_OFF + NB * 1024; j += 256) ws_i[j] = 0;
}

// 16 lanes per row: softmax tree folds (k,k+64),(k,k+32),(k,k+16) in-register,
// (k,k+8..1) via 4 shfl_xor — pairwise identical to the passing tree.
// Fused: decode + validity + LDS hist + per-image compaction.
__global__ void __launch_bounds__(256) cand_kernel(const float* __restrict__ logits,
                                                   const float* __restrict__ rel,
                                                   const float* __restrict__ props,
                                                   int* __restrict__ ws_i,
                                                   float* __restrict__ ws_f) {
  const int blk = blockIdx.x;
  const int b = blk / BPI;
  const int ib = blk - b * BPI;
  const int t = threadIdx.x;
  const int L = t & 15;      // lane within 16-lane row group
  const int grp = t >> 4;    // 0..15

  __shared__ float sbx[LCAP][4];
  __shared__ float ssb[LCAP];
  __shared__ int soidb[LCAP];
  __shared__ int lhist[1024];
  __shared__ int scnt;
  __shared__ int smaxs;
  __shared__ int sgbase;
  for (int j = t; j < 1024; j += 256) lhist[j] = 0;
  if (t == 0) { scnt = 0; smaxs = 0; }
  __syncthreads();

  int tmax = 0;  // thread-local coord max (float bits; coords >= 0)

  for (int i = 0; i < 4; ++i) {
    const int row = b * NN + ib * RPB + i * 16 + grp;
    const float* lp = logits + (size_t)row * NC;

    float lv[6];
#pragma unroll
    for (int j = 0; j < 6; ++j) {
      const int k = L + 16 * j;
      lv[j] = (k < NC) ? lp[k] : -INFINITY;
    }
    float tm0 = fmax(lv[0], lv[4]), tm1 = fmax(lv[1], lv[5]);
    float tm2 = lv[2], tm3 = lv[3];
    float um0 = fmax(tm0, tm2), um1 = fmax(tm1, tm3);
    float m = fmax(um0, um1);
    m = fmaxf(m, __shfl_xor(m, 8));
    m = fmaxf(m, __shfl_xor(m, 4));
    m = fmaxf(m, __shfl_xor(m, 2));
    m = fmaxf(m, __shfl_xor(m, 1));

    float ev[6];
#pragma unroll
    for (int j = 0; j < 6; ++j) {
      const int k = L + 16 * j;
      ev[j] = (k < NC) ? expf(lv[j] - m) : 0.0f;
    }
    float ts0 = ev[0] + ev[4], ts1 = ev[1] + ev[5];
    float ts2 = ev[2], ts3 = ev[3];
    float us0 = ts0 + ts2, us1 = ts1 + ts3;
    float sum = us0 + us1;
    sum += __shfl_xor(sum, 8);
    sum += __shfl_xor(sum, 4);
    sum += __shfl_xor(sum, 2);
    sum += __shfl_xor(sum, 1);

    const float4 p = reinterpret_cast<const float4*>(props)[row];
    const float w = p.z - p.x, h = p.w - p.y;
    const float cx = p.x + 0.5f * w, cy = p.y + 0.5f * h;

#pragma unroll
    for (int j = 0; j < 6; ++j) {
      const int c = L + 16 * j;
      if (c >= 1 && c < NC) {
        const float4 r = reinterpret_cast<const float4*>(rel)[(size_t)row * NC + c];
        const float dx = r.x / 10.0f, dy = r.y / 10.0f;
        const float dw = fminf(r.z / 5.0f, 4.135166556742356f);
        const float dh = fminf(r.w / 5.0f, 4.135166556742356f);
        const float pcx = dx * w + cx, pcy = dy * h + cy;
        const float pw = expf(dw) * w, ph = expf(dh) * h;
        float x1 = pcx - 0.5f * pw, y1 = pcy - 0.5f * ph;
        float x2 = pcx + 0.5f * pw, y2 = pcy + 0.5f * ph;
        x1 = fminf(fmaxf(x1, 0.0f), 1333.0f);
        y1 = fminf(fmaxf(y1, 0.0f), 800.0f);
        x2 = fminf(fmaxf(x2, 0.0f), 1333.0f);
        y2 = fminf(fmaxf(y2, 0.0f), 800.0f);
        const float score = ev[j] / sum;
        const float localmax = fmaxf(fmaxf(x1, y1), fmaxf(x2, y2));
        tmax = max(tmax, __float_as_int(localmax));
        const float bw = x2 - x1, bh = y2 - y1;
        if ((score > 0.05f) && (bw >= 0.01f) && (bh >= 0.01f)) {
          const int slot = atomicAdd(&scnt, 1);  // LDS; bounded by LCAP
          sbx[slot][0] = x1; sbx[slot][1] = y1;
          sbx[slot][2] = x2; sbx[slot][3] = y2;
          ssb[slot] = score;
          soidb[slot] = (row - b * NN) * CM1 + (c - 1);
          int bi = (int)(__float_as_uint(score) >> 16) - 15360;
          bi = min(max(bi, 0), 1023);
          atomicAdd(&lhist[bi], 1);
        }
      }
    }
  }
  atomicMax(&smaxs, tmax);
  __syncthreads();
  const int n = scnt;
  if (t == 0) {
    sgbase = atomicAdd(&ws_i[CNT_OFF + b], n);
    atomicMax(&ws_i[MAX_OFF + b], smaxs);
  }
  __syncthreads();
  const int gb = sgbase;
  for (int j = t; j < n; j += 256) {
    const int pos = gb + j;
    if (pos < GCAP) {
      reinterpret_cast<float4*>(ws_f + GBOX_OFF)[b * GCAP + pos] =
          make_float4(sbx[j][0], sbx[j][1], sbx[j][2], sbx[j][3]);
      ws_f[GSC_OFF + b * GCAP + pos] = ssb[j];
      ws_i[GOID_OFF + b * GCAP + pos] = soidb[j];
    }
  }
  for (int j = t; j < 1024; j += 256) {
    const int v = lhist[j];
    if (v) atomicAdd(&ws_i[HIST_OFF + b * 1024 + j], v);
  }
}

// Wide, with fused cutoff. Block-aggregated compaction: classify into LDS
// index lists, ONE global atomicAdd per list per block, then coalesced flush.
__global__ void __launch_bounds__(256) gather_kernel(int* __restrict__ ws_i,
                                                     float* __restrict__ ws_f) {
  const int b = blockIdx.x / GWB, sub = blockIdx.x % GWB;
  const int t = threadIdx.x;
  __shared__ int seg[256];
  __shared__ int best1, best2;
  __shared__ int lidxA[ACAP];   // total A <= ATHR=448 by cutoff construction
  __shared__ int lidxR[CAP];    // total R <= CAP by cutoff construction
  __shared__ int cA, cR, baseA, baseR;

  const int* H = ws_i + HIST_OFF + b * 1024;
  const int h0 = H[4 * t + 0], h1 = H[4 * t + 1];
  const int h2 = H[4 * t + 2], h3 = H[4 * t + 3];
  seg[t] = h0 + h1 + h2 + h3;
  if (t == 0) { best1 = 1024; best2 = 1024; cA = 0; cR = 0; }
  __syncthreads();
  for (int off = 1; off < 256; off <<= 1) {
    const int v = (t + off < 256) ? seg[t + off] : 0;
    __syncthreads();
    seg[t] += v;
    __syncthreads();
  }
  const int higher = (t < 255) ? seg[t + 1] : 0;
  {
    int A = higher; int cnd = 0x7FFFFFFF;
    A += h3; if (A <= CAP) cnd = 4 * t + 3;
    A += h2; if (A <= CAP) cnd = 4 * t + 2;
    A += h1; if (A <= CAP) cnd = 4 * t + 1;
    A += h0; if (A <= CAP) cnd = 4 * t + 0;
    if (cnd != 0x7FFFFFFF) atomicMin(&best1, cnd);
  }
  {
    int A = higher; int cnd = 0x7FFFFFFF;
    A += h3; if (A <= ATHR) cnd = 4 * t + 3;
    A += h2; if (A <= ATHR) cnd = 4 * t + 2;
    A += h1; if (A <= ATHR) cnd = 4 * t + 1;
    A += h0; if (A <= ATHR) cnd = 4 * t + 0;
    if (cnd != 0x7FFFFFFF) atomicMin(&best2, cnd);
  }
  __syncthreads();
  const int tk = best1, tk2 = best2;

  int M = ws_i[CNT_OFF + b];
  if (M > GCAP) M = GCAP;
  const float* gsc = ws_f + GSC_OFF + (size_t)b * GCAP;
  const int* goid = ws_i + GOID_OFF + (size_t)b * GCAP;
  const float4* gbox = reinterpret_cast<const float4*>(ws_f + GBOX_OFF) + (size_t)b * GCAP;
  float4* abox = reinterpret_cast<float4*>(ws_f + ABOX_OFF) + (size_t)b * ACAP;
  unsigned long long* akey = reinterpret_cast<unsigned long long*>(ws_i + AKEY_OFF) + (size_t)b * ACAP;
  float4* rbox = reinterpret_cast<float4*>(ws_f + RBOX_OFF) + (size_t)b * CAP;
  unsigned long long* rkey = reinterpret_cast<unsigned long long*>(ws_i + RKEY_OFF) + (size_t)b * CAP;

  // classify into LDS index lists (LDS atomics only)
  for (int j = sub * 256 + t; j < M; j += GWB * 256) {
    const float s = gsc[j];
    int bi = (int)(__float_as_uint(s) >> 16) - 15360;
    bi = min(max(bi, 0), 1023);
    if (bi >= tk2) {
      const int p = atomicAdd(&cA, 1);
      if (p < ACAP) lidxA[p] = j;
    } else if (bi >= tk) {
      const int p = atomicAdd(&cR, 1);
      if (p < CAP) lidxR[p] = j;
    }
  }
  __syncthreads();
  const int nAb = min(cA, ACAP), nRb = min(cR, CAP);
  if (t == 0) {
    baseA = atomicAdd(&ws_i[CNTA_OFF + b], nAb);
    baseR = atomicAdd(&ws_i[CNTR_OFF + b], nRb);
  }
  __syncthreads();
  for (int k = t; k < nAb; k += 256) {
    const int j = lidxA[k];
    const int pos = baseA + k;
    if (pos < ACAP) {
      abox[pos] = gbox[j];
      akey[pos] = ((unsigned long long)(__float_as_uint(gsc[j]) | 0x80000000u) << 32) |
                  (unsigned)(0xFFFFFFFFu - (unsigned)goid[j]);
    }
  }
  for (int k = t; k < nRb; k += 256) {
    const int j = lidxR[k];
    const int pos = baseR + k;
    if (pos < CAP) {
      rbox[pos] = gbox[j];
      rkey[pos] = ((unsigned long long)(__float_as_uint(gsc[j]) | 0x80000000u) << 32) |
                  (unsigned)(0xFFFFFFFFu - (unsigned)goid[j]);
    }
  }
}

// One block per image: rank-sort chunk A in LDS, single-wave sequential accept
// scan; fallback max-extract over reserve if <100 accepts (normally not taken).
__global__ void __launch_bounds__(256) nms_kernel(const int* __restrict__ ws_i,
                                                  const float* __restrict__ ws_f,
                                                  float* __restrict__ out) {
  const int b = blockIdx.x;
  const int t = threadIdx.x;
  const int lane = t & 63;
  __shared__ __align__(16) char sm[57344];
  unsigned long long* akey = (unsigned long long*)sm;            // 512 u64
  float4* abox = (float4*)(sm + 4096);                           // 512 f4
  unsigned long long* skeyS = (unsigned long long*)(sm + 12288); // 512 u64
  float4* sboxS = (float4*)(sm + 16384);                         // 512 f4
  int* slblS = (int*)(sm + 24576);                               // 512 int
  unsigned long long* rkeyS = (unsigned long long*)sm;           // 2048 u64 (alias)
  float4* rboxS = (float4*)(sm + 16384);                         // 2048 f4 (alias)
  int* rlblS = (int*)(sm + 49152);                               // 2048 int (alias)
  __shared__ float4 selbox[100];
  __shared__ unsigned long long selkey[100];
  __shared__ int sellbl[100];
  __shared__ int snacc;
  __shared__ int sneed;

  const int nA = min(ws_i[CNTA_OFF + b], ACAP);
  const int nR = min(ws_i[CNTR_OFF + b], CAP);
  const float maxp1 = __int_as_float(ws_i[MAX_OFF + b]) + 1.0f;
  const float4* gA = reinterpret_cast<const float4*>(ws_f + ABOX_OFF) + (size_t)b * ACAP;
  const unsigned long long* gAk =
      reinterpret_cast<const unsigned long long*>(ws_i + AKEY_OFF) + (size_t)b * ACAP;

  for (int j = t; j < ACAP; j += 256) {
    akey[j] = (j < nA) ? gAk[j] : 0ull;
    if (j < nA) abox[j] = gA[j];
    skeyS[j] = 0ull;
  }
  __syncthreads();

#pragma unroll
  for (int rr = 0; rr < 2; ++rr) {
    const int j = t + rr * 256;
    const unsigned long long kj = akey[j];
    if (kj != 0ull) {
      int rank = 0;
      for (int i = 0; i < ACAP; ++i) rank += (akey[i] > kj) ? 1 : 0;
      skeyS[rank] = kj;
      sboxS[rank] = abox[j];
      const unsigned oid = 0xFFFFFFFFu - (unsigned)(kj & 0xFFFFFFFFull);
      slblS[rank] = (int)(oid % 90u) + 1;
    }
  }
  __syncthreads();

  float A0x = 0.f, A0y = 0.f, A0z = 0.f, A0w = 0.f; int L0 = -1;
  float A1x = 0.f, A1y = 0.f, A1z = 0.f, A1w = 0.f; int L1 = -1;
  int nacc = 0;

  if (t < 64) {
    unsigned long long key = skeyS[0];
    float4 bb = sboxS[0];
    int lbl = slblS[0];
    for (int j = 0; j < ACAP; ++j) {
      if (key == 0ull) break;
      const int jn = (j + 1 < ACAP) ? j + 1 : j;
      const unsigned long long nk = (j + 1 < ACAP) ? skeyS[j + 1] : 0ull;
      const float4 nbb = sboxS[jn];
      const int nlb = slblS[jn];
      const float oi = (float)lbl * maxp1;
      const float q0 = bb.x + oi, q1 = bb.y + oi;
      const float q2 = bb.z + oi, q3 = bb.w + oi;
      const float a2 = (q2 - q0) * (q3 - q1);
      bool sup = false;
      if (L0 == lbl) {
        const float n0 = A0x + oi, n1 = A0y + oi, n2 = A0z + oi, n3 = A0w + oi;
        const float a1 = (n2 - n0) * (n3 - n1);
        const float ix1 = fmaxf(n0, q0), iy1 = fmaxf(n1, q1);
        const float ix2 = fminf(n2, q2), iy2 = fminf(n3, q3);
        const float inter = fmaxf(ix2 - ix1, 0.0f) * fmaxf(iy2 - iy1, 0.0f);
        const float iou = inter / ((a1 + a2) - inter);
        sup = (iou > 0.5f);
      }
      if (L1 == lbl) {
        const float n0 = A1x + oi, n1 = A1y + oi, n2 = A1z + oi, n3 = A1w + oi;
        const float a1 = (n2 - n0) * (n3 - n1);
        const float ix1 = fmaxf(n0, q0), iy1 = fmaxf(n1, q1);
        const float ix2 = fminf(n2, q2), iy2 = fminf(n3, q3);
        const float inter = fmaxf(ix2 - ix1, 0.0f) * fmaxf(iy2 - iy1, 0.0f);
        const float iou = inter / ((a1 + a2) - inter);
        sup = sup || (iou > 0.5f);
      }
      if (!__any(sup ? 1 : 0)) {
        if (nacc < 64) {
          if (lane == nacc) { A0x = bb.x; A0y = bb.y; A0z = bb.z; A0w = bb.w; L0 = lbl; }
        } else {
          if (lane == nacc - 64) { A1x = bb.x; A1y = bb.y; A1z = bb.z; A1w = bb.w; L1 = lbl; }
        }
        if (lane == 0) { selbox[nacc] = bb; selkey[nacc] = key; sellbl[nacc] = lbl; }
        ++nacc;
        if (nacc == 100) break;
      }
      key = nk; bb = nbb; lbl = nlb;
    }
    if (lane == 0) { snacc = nacc; sneed = (nacc < 100 && nR > 0) ? 1 : 0; }
  }
  __syncthreads();

  if (sneed) {  // normally never taken: continue over reserve in exact order
    const float4* gR = reinterpret_cast<const float4*>(ws_f + RBOX_OFF) + (size_t)b * CAP;
    const unsigned long long* gRk =
        reinterpret_cast<const unsigned long long*>(ws_i + RKEY_OFF) + (size_t)b * CAP;
    for (int j = t; j < CAP; j += 256) {
      const unsigned long long k = (j < nR) ? gRk[j] : 0ull;
      rkeyS[j] = k;
      if (j < nR) {
        rboxS[j] = gR[j];
        const unsigned oid = 0xFFFFFFFFu - (unsigned)(k & 0xFFFFFFFFull);
        rlblS[j] = (int)(oid % 90u) + 1;
      }
    }
    __syncthreads();
    if (t < 64) {
      while (nacc < 100) {
        unsigned long long mk = 0ull; int mi = 0;
        for (int j = lane; j < nR; j += 64) {
          const unsigned long long k = rkeyS[j];
          if (k > mk) { mk = k; mi = j; }
        }
        for (int mm = 1; mm < 64; mm <<= 1) {
          const unsigned long long ok = __shfl_xor(mk, mm);
          const int om = __shfl_xor(mi, mm);
          if (ok > mk) { mk = ok; mi = om; }
        }
        if (mk == 0ull) break;
        if (lane == 0) rkeyS[mi] = 0ull;
        __asm__ volatile("s_waitcnt lgkmcnt(0)" ::: "memory");
        const int lbl = rlblS[mi];
        const float4 bb = rboxS[mi];
        const float oi = (float)lbl * maxp1;
        const float q0 = bb.x + oi, q1 = bb.y + oi;
        const float q2 = bb.z + oi, q3 = bb.w + oi;
        const float a2 = (q2 - q0) * (q3 - q1);
        bool sup = false;
        if (L0 == lbl) {
          const float n0 = A0x + oi, n1 = A0y + oi, n2 = A0z + oi, n3 = A0w + oi;
          const float a1 = (n2 - n0) * (n3 - n1);
          const float ix1 = fmaxf(n0, q0), iy1 = fmaxf(n1, q1);
          const float ix2 = fminf(n2, q2), iy2 = fminf(n3, q3);
          const float inter = fmaxf(ix2 - ix1, 0.0f) * fmaxf(iy2 - iy1, 0.0f);
          const float iou = inter / ((a1 + a2) - inter);
          sup = (iou > 0.5f);
        }
        if (L1 == lbl) {
          const float n0 = A1x + oi, n1 = A1y + oi, n2 = A1z + oi, n3 = A1w + oi;
          const float a1 = (n2 - n0) * (n3 - n1);
          const float ix1 = fmaxf(n0, q0), iy1 = fmaxf(n1, q1);
          const float ix2 = fminf(n2, q2), iy2 = fminf(n3, q3);
          const float inter = fmaxf(ix2 - ix1, 0.0f) * fmaxf(iy2 - iy1, 0.0f);
          const float iou = inter / ((a1 + a2) - inter);
          sup = sup || (iou > 0.5f);
        }
        if (!__any(sup ? 1 : 0)) {
          if (nacc < 64) {
            if (lane == nacc) { A0x = bb.x; A0y = bb.y; A0z = bb.z; A0w = bb.w; L0 = lbl; }
          } else {
            if (lane == nacc - 64) { A1x = bb.x; A1y = bb.y; A1z = bb.z; A1w = bb.w; L1 = lbl; }
          }
          if (lane == 0) { selbox[nacc] = bb; selkey[nacc] = mk; sellbl[nacc] = lbl; }
          ++nacc;
        }
      }
      if (lane == 0) snacc = nacc;
    }
    __syncthreads();
  }

  const int nf = snacc;
  for (int k2 = t; k2 < 100; k2 += 256) {
    float o0 = 0.f, o1 = 0.f, o2 = 0.f, o3 = 0.f, sc = 0.f, lb = 0.f;
    if (k2 < nf) {
      const float4 v = selbox[k2];
      o0 = v.x; o1 = v.y; o2 = v.z; o3 = v.w;
      sc = __uint_as_float((unsigned)(selkey[k2] >> 32) & 0x7FFFFFFFu);
      lb = (float)sellbl[k2];
    }
    float* ob = out + ((size_t)b * 100 + k2) * 4;
    ob[0] = o0; ob[1] = o1; ob[2] = o2; ob[3] = o3;
    out[NB * 100 * 4 + b * 100 + k2] = sc;
    out[NB * 100 * 4 + NB * 100 + b * 100 + k2] = lb;
  }
}

extern "C" void kernel_launch(void* const* d_in, const int* in_sizes, int n_in,
                              void* d_out, int out_size, void* d_ws, size_t ws_size,
                              hipStream_t stream) {
  const float* logits = (const float*)d_in[0];
  const float* rel = (const float*)d_in[1];
  const float* props = (const float*)d_in[2];
  float* out = (float*)d_out;
  int* ws_i = (int*)d_ws;
  float* ws_f = (float*)d_ws;

  init_kernel<<<17, 256, 0, stream>>>(ws_i);
  cand_kernel<<<NB * BPI, 256, 0, stream>>>(logits, rel, props, ws_i, ws_f);
  gather_kernel<<<NB * GWB, 256, 0, stream>>>(ws_i, ws_f);
  nms_kernel<<<NB, 256, 0, stream>>>(ws_i, ws_f, out);
}

// Round 9
// 92.344 us; speedup vs baseline: 7.2557x; 1.0902x over previous
//
#include <hip/hip_runtime.h>
#include <math.h>

#pragma clang fp contract(off)

#define NB 4
#define NN 8000
#define NC 91
#define CM1 90
#define CAP 2048          // outer kept bound (proven sufficient rounds 1-8)
#define ACAP 256          // chunk-A padded size
#define ATHR 192          // chunk-A histogram bound
#define GCAP 65536
#define RPB 64            // rows per block in cand_kernel
#define BPI (NN / RPB)    // 125 blocks per image
#define LCAP 1216         // = RPB*19 (hard bound: <=19 scores>0.05 per row)
#define GWB 16            // wide blocks per image for gather

// ws layout (32-bit words)
#define CNT_OFF 0    // NB valid count
#define MAX_OFF 4    // NB coord-max bits
#define CNTA_OFF 16  // NB
#define CNTR_OFF 20  // NB
#define HIST_OFF 32  // NB*1024
#define GBOX_OFF 4128                       // NB*GCAP float4
#define GSC_OFF (GBOX_OFF + NB * GCAP * 4)
#define GOID_OFF (GSC_OFF + NB * GCAP)
#define ABOX_OFF (GOID_OFF + NB * GCAP)     // NB*ACAP float4
#define AKEY_OFF (ABOX_OFF + NB * ACAP * 4) // NB*ACAP u64 (2 words each)
#define RBOX_OFF (AKEY_OFF + NB * ACAP * 2) // NB*CAP float4
#define RKEY_OFF (RBOX_OFF + NB * CAP * 4)  // NB*CAP u64

__global__ void init_kernel(int* ws_i) {
  for (int j = threadIdx.x; j < HIST_OFF + NB * 1024; j += 256) ws_i[j] = 0;
}

// 16 lanes per row: softmax tree folds in-register + 4 shfl_xor.
// Fused: decode + validity + LDS hist + per-image compaction.
__global__ void __launch_bounds__(256) cand_kernel(const float* __restrict__ logits,
                                                   const float* __restrict__ rel,
                                                   const float* __restrict__ props,
                                                   int* __restrict__ ws_i,
                                                   float* __restrict__ ws_f) {
  const int blk = blockIdx.x;
  const int b = blk / BPI;
  const int ib = blk - b * BPI;
  const int t = threadIdx.x;
  const int L = t & 15;
  const int grp = t >> 4;

  __shared__ float sbx[LCAP][4];
  __shared__ float ssb[LCAP];
  __shared__ int soidb[LCAP];
  __shared__ int lhist[1024];
  __shared__ int scnt;
  __shared__ int smaxs;
  __shared__ int sgbase;
  for (int j = t; j < 1024; j += 256) lhist[j] = 0;
  if (t == 0) { scnt = 0; smaxs = 0; }
  __syncthreads();

  int tmax = 0;

  for (int i = 0; i < 4; ++i) {
    const int row = b * NN + ib * RPB + i * 16 + grp;
    const float* lp = logits + (size_t)row * NC;

    float lv[6];
#pragma unroll
    for (int j = 0; j < 6; ++j) {
      const int k = L + 16 * j;
      lv[j] = (k < NC) ? lp[k] : -INFINITY;
    }
    float tm0 = fmax(lv[0], lv[4]), tm1 = fmax(lv[1], lv[5]);
    float tm2 = lv[2], tm3 = lv[3];
    float um0 = fmax(tm0, tm2), um1 = fmax(tm1, tm3);
    float m = fmax(um0, um1);
    m = fmaxf(m, __shfl_xor(m, 8));
    m = fmaxf(m, __shfl_xor(m, 4));
    m = fmaxf(m, __shfl_xor(m, 2));
    m = fmaxf(m, __shfl_xor(m, 1));

    float ev[6];
#pragma unroll
    for (int j = 0; j < 6; ++j) {
      const int k = L + 16 * j;
      ev[j] = (k < NC) ? expf(lv[j] - m) : 0.0f;
    }
    float ts0 = ev[0] + ev[4], ts1 = ev[1] + ev[5];
    float ts2 = ev[2], ts3 = ev[3];
    float us0 = ts0 + ts2, us1 = ts1 + ts3;
    float sum = us0 + us1;
    sum += __shfl_xor(sum, 8);
    sum += __shfl_xor(sum, 4);
    sum += __shfl_xor(sum, 2);
    sum += __shfl_xor(sum, 1);

    const float4 p = reinterpret_cast<const float4*>(props)[row];
    const float w = p.z - p.x, h = p.w - p.y;
    const float cx = p.x + 0.5f * w, cy = p.y + 0.5f * h;

#pragma unroll
    for (int j = 0; j < 6; ++j) {
      const int c = L + 16 * j;
      if (c >= 1 && c < NC) {
        const float4 r = reinterpret_cast<const float4*>(rel)[(size_t)row * NC + c];
        const float dx = r.x / 10.0f, dy = r.y / 10.0f;
        const float dw = fminf(r.z / 5.0f, 4.135166556742356f);
        const float dh = fminf(r.w / 5.0f, 4.135166556742356f);
        const float pcx = dx * w + cx, pcy = dy * h + cy;
        const float pw = expf(dw) * w, ph = expf(dh) * h;
        float x1 = pcx - 0.5f * pw, y1 = pcy - 0.5f * ph;
        float x2 = pcx + 0.5f * pw, y2 = pcy + 0.5f * ph;
        x1 = fminf(fmaxf(x1, 0.0f), 1333.0f);
        y1 = fminf(fmaxf(y1, 0.0f), 800.0f);
        x2 = fminf(fmaxf(x2, 0.0f), 1333.0f);
        y2 = fminf(fmaxf(y2, 0.0f), 800.0f);
        const float score = ev[j] / sum;
        const float localmax = fmaxf(fmaxf(x1, y1), fmaxf(x2, y2));
        tmax = max(tmax, __float_as_int(localmax));
        const float bw = x2 - x1, bh = y2 - y1;
        if ((score > 0.05f) && (bw >= 0.01f) && (bh >= 0.01f)) {
          const int slot = atomicAdd(&scnt, 1);  // LDS; bounded by LCAP
          sbx[slot][0] = x1; sbx[slot][1] = y1;
          sbx[slot][2] = x2; sbx[slot][3] = y2;
          ssb[slot] = score;
          soidb[slot] = (row - b * NN) * CM1 + (c - 1);
          int bi = (int)(__float_as_uint(score) >> 16) - 15360;
          bi = min(max(bi, 0), 1023);
          atomicAdd(&lhist[bi], 1);
        }
      }
    }
  }
  atomicMax(&smaxs, tmax);
  __syncthreads();
  const int n = scnt;
  if (t == 0) {
    sgbase = atomicAdd(&ws_i[CNT_OFF + b], n);
    atomicMax(&ws_i[MAX_OFF + b], smaxs);
  }
  __syncthreads();
  const int gb = sgbase;
  for (int j = t; j < n; j += 256) {
    const int pos = gb + j;
    if (pos < GCAP) {
      reinterpret_cast<float4*>(ws_f + GBOX_OFF)[b * GCAP + pos] =
          make_float4(sbx[j][0], sbx[j][1], sbx[j][2], sbx[j][3]);
      ws_f[GSC_OFF + b * GCAP + pos] = ssb[j];
      ws_i[GOID_OFF + b * GCAP + pos] = soidb[j];
    }
  }
  for (int j = t; j < 1024; j += 256) {
    const int v = lhist[j];
    if (v) atomicAdd(&ws_i[HIST_OFF + b * 1024 + j], v);
  }
}

// Wide, with fused cutoff. Block-aggregated compaction: classify into LDS
// index lists, ONE global atomicAdd per list per block, then coalesced flush.
__global__ void __launch_bounds__(256) gather_kernel(int* __restrict__ ws_i,
                                                     float* __restrict__ ws_f) {
  const int b = blockIdx.x / GWB, sub = blockIdx.x % GWB;
  const int t = threadIdx.x;
  __shared__ int seg[256];
  __shared__ int best1, best2;
  __shared__ int lidxA[ACAP];   // total A <= ATHR=192 by cutoff construction
  __shared__ int lidxR[CAP];    // total R <= CAP by cutoff construction
  __shared__ int cA, cR, baseA, baseR;

  const int* H = ws_i + HIST_OFF + b * 1024;
  const int h0 = H[4 * t + 0], h1 = H[4 * t + 1];
  const int h2 = H[4 * t + 2], h3 = H[4 * t + 3];
  seg[t] = h0 + h1 + h2 + h3;
  if (t == 0) { best1 = 1024; best2 = 1024; cA = 0; cR = 0; }
  __syncthreads();
  for (int off = 1; off < 256; off <<= 1) {
    const int v = (t + off < 256) ? seg[t + off] : 0;
    __syncthreads();
    seg[t] += v;
    __syncthreads();
  }
  const int higher = (t < 255) ? seg[t + 1] : 0;
  {
    int A = higher; int cnd = 0x7FFFFFFF;
    A += h3; if (A <= CAP) cnd = 4 * t + 3;
    A += h2; if (A <= CAP) cnd = 4 * t + 2;
    A += h1; if (A <= CAP) cnd = 4 * t + 1;
    A += h0; if (A <= CAP) cnd = 4 * t + 0;
    if (cnd != 0x7FFFFFFF) atomicMin(&best1, cnd);
  }
  {
    int A = higher; int cnd = 0x7FFFFFFF;
    A += h3; if (A <= ATHR) cnd = 4 * t + 3;
    A += h2; if (A <= ATHR) cnd = 4 * t + 2;
    A += h1; if (A <= ATHR) cnd = 4 * t + 1;
    A += h0; if (A <= ATHR) cnd = 4 * t + 0;
    if (cnd != 0x7FFFFFFF) atomicMin(&best2, cnd);
  }
  __syncthreads();
  const int tk = best1, tk2 = best2;

  int M = ws_i[CNT_OFF + b];
  if (M > GCAP) M = GCAP;
  const float* gsc = ws_f + GSC_OFF + (size_t)b * GCAP;
  const int* goid = ws_i + GOID_OFF + (size_t)b * GCAP;
  const float4* gbox = reinterpret_cast<const float4*>(ws_f + GBOX_OFF) + (size_t)b * GCAP;
  float4* abox = reinterpret_cast<float4*>(ws_f + ABOX_OFF) + (size_t)b * ACAP;
  unsigned long long* akey = reinterpret_cast<unsigned long long*>(ws_i + AKEY_OFF) + (size_t)b * ACAP;
  float4* rbox = reinterpret_cast<float4*>(ws_f + RBOX_OFF) + (size_t)b * CAP;
  unsigned long long* rkey = reinterpret_cast<unsigned long long*>(ws_i + RKEY_OFF) + (size_t)b * CAP;

  for (int j = sub * 256 + t; j < M; j += GWB * 256) {
    const float s = gsc[j];
    int bi = (int)(__float_as_uint(s) >> 16) - 15360;
    bi = min(max(bi, 0), 1023);
    if (bi >= tk2) {
      const int p = atomicAdd(&cA, 1);
      if (p < ACAP) lidxA[p] = j;
    } else if (bi >= tk) {
      const int p = atomicAdd(&cR, 1);
      if (p < CAP) lidxR[p] = j;
    }
  }
  __syncthreads();
  const int nAb = min(cA, ACAP), nRb = min(cR, CAP);
  if (t == 0) {
    baseA = atomicAdd(&ws_i[CNTA_OFF + b], nAb);
    baseR = atomicAdd(&ws_i[CNTR_OFF + b], nRb);
  }
  __syncthreads();
  for (int k = t; k < nAb; k += 256) {
    const int j = lidxA[k];
    const int pos = baseA + k;
    if (pos < ACAP) {
      abox[pos] = gbox[j];
      akey[pos] = ((unsigned long long)(__float_as_uint(gsc[j]) | 0x80000000u) << 32) |
                  (unsigned)(0xFFFFFFFFu - (unsigned)goid[j]);
    }
  }
  for (int k = t; k < nRb; k += 256) {
    const int j = lidxR[k];
    const int pos = baseR + k;
    if (pos < CAP) {
      rbox[pos] = gbox[j];
      rkey[pos] = ((unsigned long long)(__float_as_uint(gsc[j]) | 0x80000000u) << 32) |
                  (unsigned)(0xFFFFFFFFu - (unsigned)goid[j]);
    }
  }
}

// One block per image: unrolled rank-sort of chunk A (<=256) in LDS, then a
// single-wave sequential accept scan with prefetch-depth-2; exact fallback
// max-extract over the reserve if <100 accepts (normally not taken).
__global__ void __launch_bounds__(256) nms_kernel(const int* __restrict__ ws_i,
                                                  const float* __restrict__ ws_f,
                                                  float* __restrict__ out) {
  const int b = blockIdx.x;
  const int t = threadIdx.x;
  const int lane = t & 63;
  __shared__ __align__(16) char sm[57344];
  unsigned long long* akey = (unsigned long long*)sm;            // 256 u64: 0..2048
  float4* abox = (float4*)(sm + 2048);                           // 256 f4: ..6144
  unsigned long long* skeyS = (unsigned long long*)(sm + 6144);  // 256 u64: ..8192
  float4* sboxS = (float4*)(sm + 8192);                          // 256 f4: ..12288
  int* slblS = (int*)(sm + 12288);                               // 256 int: ..13312
  unsigned long long* rkeyS = (unsigned long long*)sm;           // 2048 u64 (alias)
  float4* rboxS = (float4*)(sm + 16384);                         // 2048 f4 (alias)
  int* rlblS = (int*)(sm + 49152);                               // 2048 int (alias)
  __shared__ float4 selbox[100];
  __shared__ unsigned long long selkey[100];
  __shared__ int sellbl[100];
  __shared__ int snacc;
  __shared__ int sneed;

  const int nA = min(ws_i[CNTA_OFF + b], ACAP);
  const int nR = min(ws_i[CNTR_OFF + b], CAP);
  const float maxp1 = __int_as_float(ws_i[MAX_OFF + b]) + 1.0f;
  const float4* gA = reinterpret_cast<const float4*>(ws_f + ABOX_OFF) + (size_t)b * ACAP;
  const unsigned long long* gAk =
      reinterpret_cast<const unsigned long long*>(ws_i + AKEY_OFF) + (size_t)b * ACAP;

  // load chunk A (one slot per thread)
  akey[t] = (t < nA) ? gAk[t] : 0ull;
  if (t < nA) abox[t] = gA[t];
  skeyS[t] = 0ull;
  __syncthreads();

  // exact rank-sort (keys unique); unrolled so LDS broadcast reads pipeline
  {
    const unsigned long long kj = akey[t];
    if (kj != 0ull) {
      int rank = 0;
#pragma unroll 16
      for (int i = 0; i < ACAP; ++i) rank += (akey[i] > kj) ? 1 : 0;
      skeyS[rank] = kj;
      sboxS[rank] = abox[t];
      const unsigned oid = 0xFFFFFFFFu - (unsigned)(kj & 0xFFFFFFFFull);
      slblS[rank] = (int)(oid % 90u) + 1;
    }
  }
  __syncthreads();

  float A0x = 0.f, A0y = 0.f, A0z = 0.f, A0w = 0.f; int L0 = -1;
  float A1x = 0.f, A1y = 0.f, A1z = 0.f, A1w = 0.f; int L1 = -1;
  int nacc = 0;

  if (t < 64) {
    // prefetch depth 2
    unsigned long long k0 = skeyS[0], k1 = skeyS[1];
    float4 b0 = sboxS[0], b1 = sboxS[1];
    int l0 = slblS[0], l1 = slblS[1];
    for (int j = 0; j < ACAP; ++j) {
      if (k0 == 0ull) break;
      const int jp = j + 2;
      unsigned long long k2 = 0ull;
      float4 b2 = make_float4(0.f, 0.f, 0.f, 0.f);
      int l2 = 0;
      if (jp < ACAP) { k2 = skeyS[jp]; b2 = sboxS[jp]; l2 = slblS[jp]; }
      const float oi = (float)l0 * maxp1;
      const float q0 = b0.x + oi, q1 = b0.y + oi;
      const float q2 = b0.z + oi, q3 = b0.w + oi;
      const float a2 = (q2 - q0) * (q3 - q1);
      bool sup = false;
      if (L0 == l0) {
        const float n0 = A0x + oi, n1 = A0y + oi, n2 = A0z + oi, n3 = A0w + oi;
        const float a1 = (n2 - n0) * (n3 - n1);
        const float ix1 = fmaxf(n0, q0), iy1 = fmaxf(n1, q1);
        const float ix2 = fminf(n2, q2), iy2 = fminf(n3, q3);
        const float inter = fmaxf(ix2 - ix1, 0.0f) * fmaxf(iy2 - iy1, 0.0f);
        const float iou = inter / ((a1 + a2) - inter);
        sup = (iou > 0.5f);
      }
      if (L1 == l0) {
        const float n0 = A1x + oi, n1 = A1y + oi, n2 = A1z + oi, n3 = A1w + oi;
        const float a1 = (n2 - n0) * (n3 - n1);
        const float ix1 = fmaxf(n0, q0), iy1 = fmaxf(n1, q1);
        const float ix2 = fminf(n2, q2), iy2 = fminf(n3, q3);
        const float inter = fmaxf(ix2 - ix1, 0.0f) * fmaxf(iy2 - iy1, 0.0f);
        const float iou = inter / ((a1 + a2) - inter);
        sup = sup || (iou > 0.5f);
      }
      if (!__any(sup ? 1 : 0)) {
        if (nacc < 64) {
          if (lane == nacc) { A0x = b0.x; A0y = b0.y; A0z = b0.z; A0w = b0.w; L0 = l0; }
        } else {
          if (lane == nacc - 64) { A1x = b0.x; A1y = b0.y; A1z = b0.z; A1w = b0.w; L1 = l0; }
        }
        if (lane == 0) { selbox[nacc] = b0; selkey[nacc] = k0; sellbl[nacc] = l0; }
        ++nacc;
        if (nacc == 100) break;
      }
      k0 = k1; b0 = b1; l0 = l1;
      k1 = k2; b1 = b2; l1 = l2;
    }
    if (lane == 0) { snacc = nacc; sneed = (nacc < 100 && nR > 0) ? 1 : 0; }
  }
  __syncthreads();

  if (sneed) {  // normally never taken: continue over reserve in exact order
    const float4* gR = reinterpret_cast<const float4*>(ws_f + RBOX_OFF) + (size_t)b * CAP;
    const unsigned long long* gRk =
        reinterpret_cast<const unsigned long long*>(ws_i + RKEY_OFF) + (size_t)b * CAP;
    for (int j = t; j < CAP; j += 256) {
      const unsigned long long k = (j < nR) ? gRk[j] : 0ull;
      rkeyS[j] = k;
      if (j < nR) {
        rboxS[j] = gR[j];
        const unsigned oid = 0xFFFFFFFFu - (unsigned)(k & 0xFFFFFFFFull);
        rlblS[j] = (int)(oid % 90u) + 1;
      }
    }
    __syncthreads();
    if (t < 64) {
      while (nacc < 100) {
        unsigned long long mk = 0ull; int mi = 0;
        for (int j = lane; j < nR; j += 64) {
          const unsigned long long k = rkeyS[j];
          if (k > mk) { mk = k; mi = j; }
        }
        for (int mm = 1; mm < 64; mm <<= 1) {
          const unsigned long long ok = __shfl_xor(mk, mm);
          const int om = __shfl_xor(mi, mm);
          if (ok > mk) { mk = ok; mi = om; }
        }
        if (mk == 0ull) break;
        if (lane == 0) rkeyS[mi] = 0ull;
        __asm__ volatile("s_waitcnt lgkmcnt(0)" ::: "memory");
        const int lbl = rlblS[mi];
        const float4 bb = rboxS[mi];
        const float oi = (float)lbl * maxp1;
        const float q0 = bb.x + oi, q1 = bb.y + oi;
        const float q2 = bb.z + oi, q3 = bb.w + oi;
        const float a2 = (q2 - q0) * (q3 - q1);
        bool sup = false;
        if (L0 == lbl) {
          const float n0 = A0x + oi, n1 = A0y + oi, n2 = A0z + oi, n3 = A0w + oi;
          const float a1 = (n2 - n0) * (n3 - n1);
          const float ix1 = fmaxf(n0, q0), iy1 = fmaxf(n1, q1);
          const float ix2 = fminf(n2, q2), iy2 = fminf(n3, q3);
          const float inter = fmaxf(ix2 - ix1, 0.0f) * fmaxf(iy2 - iy1, 0.0f);
          const float iou = inter / ((a1 + a2) - inter);
          sup = (iou > 0.5f);
        }
        if (L1 == lbl) {
          const float n0 = A1x + oi, n1 = A1y + oi, n2 = A1z + oi, n3 = A1w + oi;
          const float a1 = (n2 - n0) * (n3 - n1);
          const float ix1 = fmaxf(n0, q0), iy1 = fmaxf(n1, q1);
          const float ix2 = fminf(n2, q2), iy2 = fminf(n3, q3);
          const float inter = fmaxf(ix2 - ix1, 0.0f) * fmaxf(iy2 - iy1, 0.0f);
          const float iou = inter / ((a1 + a2) - inter);
          sup = sup || (iou > 0.5f);
        }
        if (!__any(sup ? 1 : 0)) {
          if (nacc < 64) {
            if (lane == nacc) { A0x = bb.x; A0y = bb.y; A0z = bb.z; A0w = bb.w; L0 = lbl; }
          } else {
            if (lane == nacc - 64) { A1x = bb.x; A1y = bb.y; A1z = bb.z; A1w = bb.w; L1 = lbl; }
          }
          if (lane == 0) { selbox[nacc] = bb; selkey[nacc] = mk; sellbl[nacc] = lbl; }
          ++nacc;
        }
      }
      if (lane == 0) snacc = nacc;
    }
    __syncthreads();
  }

  const int nf = snacc;
  for (int k2 = t; k2 < 100; k2 += 256) {
    float o0 = 0.f, o1 = 0.f, o2 = 0.f, o3 = 0.f, sc = 0.f, lb = 0.f;
    if (k2 < nf) {
      const float4 v = selbox[k2];
      o0 = v.x; o1 = v.y; o2 = v.z; o3 = v.w;
      sc = __uint_as_float((unsigned)(selkey[k2] >> 32) & 0x7FFFFFFFu);
      lb = (float)sellbl[k2];
    }
    float* ob = out + ((size_t)b * 100 + k2) * 4;
    ob[0] = o0; ob[1] = o1; ob[2] = o2; ob[3] = o3;
    out[NB * 100 * 4 + b * 100 + k2] = sc;
    out[NB * 100 * 4 + NB * 100 + b * 100 + k2] = lb;
  }
}

extern "C" void kernel_launch(void* const* d_in, const int* in_sizes, int n_in,
                              void* d_out, int out_size, void* d_ws, size_t ws_size,
                              hipStream_t stream) {
  const float* logits = (const float*)d_in[0];
  const float* rel = (const float*)d_in[1];
  const float* props = (const float*)d_in[2];
  float* out = (float*)d_out;
  int* ws_i = (int*)d_ws;
  float* ws_f = (float*)d_ws;

  init_kernel<<<17, 256, 0, stream>>>(ws_i);
  cand_kernel<<<NB * BPI, 256, 0, stream>>>(logits, rel, props, ws_i, ws_f);
  gather_kernel<<<NB * GWB, 256, 0, stream>>>(ws_i, ws_f);
  nms_kernel<<<NB, 256, 0, stream>>>(ws_i, ws_f, out);
}